// Round 5
// baseline (359.199 us; speedup 1.0000x reference)
//
#include <hip/hip_runtime.h>

#define NN 50000
#define NE 800000

typedef __attribute__((ext_vector_type(8))) short bf16x8;
typedef __attribute__((ext_vector_type(4))) float f32x4;

__device__ inline short f2bf(float f) {
    union { float f; unsigned u; } v; v.f = f;
    unsigned r = v.u + 0x7fffu + ((v.u >> 16) & 1u);
    return (short)(r >> 16);
}
__device__ inline float bf2f(short s) {
    union { unsigned u; float f; } v;
    v.u = ((unsigned)(unsigned short)s) << 16;
    return v.f;
}

// ---------------- CSR build ----------------
__global__ __launch_bounds__(256) void count_deg_kernel(const int* __restrict__ dst,
                                                        int* __restrict__ deg, int n) {
    int e = blockIdx.x * 256 + threadIdx.x;
    if (e < n) atomicAdd(&deg[dst[e]], 1);
}

__global__ __launch_bounds__(256) void scan1_kernel(const int* __restrict__ deg,
                                                    int* __restrict__ off,
                                                    int* __restrict__ bsum, int n) {
    __shared__ int s[256];
    int t = threadIdx.x;
    int i = blockIdx.x * 256 + t;
    int v = (i < n) ? deg[i] : 0;
    s[t] = v;
    __syncthreads();
    for (int d = 1; d < 256; d <<= 1) {
        int u = (t >= d) ? s[t - d] : 0;
        __syncthreads();
        s[t] += u;
        __syncthreads();
    }
    if (i < n) off[i] = s[t] - v;
    if (t == 255) bsum[blockIdx.x] = s[255];
}

__global__ __launch_bounds__(256) void scan2_kernel(int* __restrict__ bsum, int nb) {
    __shared__ int s[256];
    int t = threadIdx.x;
    int v = (t < nb) ? bsum[t] : 0;
    s[t] = v;
    __syncthreads();
    for (int d = 1; d < 256; d <<= 1) {
        int u = (t >= d) ? s[t - d] : 0;
        __syncthreads();
        s[t] += u;
        __syncthreads();
    }
    if (t < nb) bsum[t] = s[t] - v;
}

__global__ __launch_bounds__(256) void scan3_kernel(int* __restrict__ off,
                                                    const int* __restrict__ bsum,
                                                    int* __restrict__ cursor, int n, int total) {
    int i = blockIdx.x * 256 + threadIdx.x;
    if (i < n) {
        int v = off[i] + bsum[i >> 8];
        off[i] = v;
        cursor[i] = v;
    }
    if (i == 0) off[n] = total;
}

// fill CSR; optionally record original edge id per position
__global__ __launch_bounds__(256) void fill_kernel(const int* __restrict__ src,
                                                   const int* __restrict__ dst,
                                                   int* __restrict__ cursor,
                                                   int* __restrict__ col,
                                                   int* __restrict__ eid, int n) {
    int e = blockIdx.x * 256 + threadIdx.x;
    if (e < n) {
        int p = atomicAdd(&cursor[dst[e]], 1);
        col[p] = src[e];
        if (eid) eid[p] = e;
    }
}

// per-position dst (ushort) from CSR ranges
__global__ __launch_bounds__(256) void edst_fill_kernel(const int* __restrict__ off,
                                                        unsigned short* __restrict__ edst, int n) {
    int i = blockIdx.x * 256 + threadIdx.x;
    if (i < n) {
        int p0 = off[i], p1 = off[i + 1];
        for (int p = p0; p < p1; ++p) edst[p] = (unsigned short)i;
    }
}

// ---------------- f32 -> bf16 convert (8 elems/thread) ----------------
__global__ __launch_bounds__(256) void cvt_bf16_kernel(const float* __restrict__ in,
                                                       short* __restrict__ outb, int n8) {
    int t = blockIdx.x * 256 + threadIdx.x;
    if (t >= n8) return;
    const float4* p = (const float4*)(in + (size_t)t * 8);
    float4 v0 = p[0], v1 = p[1];
    bf16x8 o;
    o[0] = f2bf(v0.x); o[1] = f2bf(v0.y); o[2] = f2bf(v0.z); o[3] = f2bf(v0.w);
    o[4] = f2bf(v1.x); o[5] = f2bf(v1.y); o[6] = f2bf(v1.z); o[7] = f2bf(v1.w);
    *(bf16x8*)(outb + (size_t)t * 8) = o;
}

// ---------------- pack B = [B0;B1] (f32 row-major, K x N) into bf16 MFMA fragments ----
__global__ __launch_bounds__(256) void pack_b_kernel(
    const float* __restrict__ B0, const float* __restrict__ B1,
    int K0, int K, int N, short* __restrict__ out) {
    int t = blockIdx.x * 256 + threadIdx.x;
    int total = (N >> 4) * (K >> 5) * 64;
    if (t >= total) return;
    int l = t & 63;
    int fs = t >> 6;
    int KS = K >> 5;
    int ct = fs / KS, ks = fs - ct * KS;
    int coln = ct * 16 + (l & 15);
    int k0 = ks * 32 + (l >> 4) * 8;
    bf16x8 v;
#pragma unroll
    for (int j = 0; j < 8; ++j) {
        int k = k0 + j;
        float f = (k < K0) ? B0[(size_t)k * N + coln] : B1[(size_t)(k - K0) * N + coln];
        v[j] = f2bf(f);
    }
    *(bf16x8*)(out + (size_t)t * 8) = v;
}

// ---------------- mean aggregation: 8 lanes/node, 16 cols/lane, 4 rows in flight ----
__global__ __launch_bounds__(256) void agg_mean_kernel(
    const short* __restrict__ hbase, const int* __restrict__ off,
    const int* __restrict__ col, short* __restrict__ meanb, int n) {
    int t = blockIdx.x * 256 + threadIdx.x;
    int node = t >> 3, q = t & 7;
    if (node >= n) return;
    int p0 = off[node], p1 = off[node + 1];
    float a[16];
#pragma unroll
    for (int k = 0; k < 16; ++k) a[k] = 0.f;
    int qo = q * 16;
    int p = p0;
    for (; p + 3 < p1; p += 4) {
        int c0 = col[p], c1 = col[p + 1], c2 = col[p + 2], c3 = col[p + 3];
        const short* r0 = hbase + (size_t)c0 * 128 + qo;
        const short* r1 = hbase + (size_t)c1 * 128 + qo;
        const short* r2 = hbase + (size_t)c2 * 128 + qo;
        const short* r3 = hbase + (size_t)c3 * 128 + qo;
        bf16x8 u0a = *(const bf16x8*)r0, u0b = *(const bf16x8*)(r0 + 8);
        bf16x8 u1a = *(const bf16x8*)r1, u1b = *(const bf16x8*)(r1 + 8);
        bf16x8 u2a = *(const bf16x8*)r2, u2b = *(const bf16x8*)(r2 + 8);
        bf16x8 u3a = *(const bf16x8*)r3, u3b = *(const bf16x8*)(r3 + 8);
#pragma unroll
        for (int k = 0; k < 8; ++k) {
            a[k]     += (bf2f(u0a[k]) + bf2f(u1a[k])) + (bf2f(u2a[k]) + bf2f(u3a[k]));
            a[k + 8] += (bf2f(u0b[k]) + bf2f(u1b[k])) + (bf2f(u2b[k]) + bf2f(u3b[k]));
        }
    }
    for (; p < p1; ++p) {
        const short* r0 = hbase + (size_t)col[p] * 128 + qo;
        bf16x8 u0 = *(const bf16x8*)r0;
        bf16x8 u1 = *(const bf16x8*)(r0 + 8);
#pragma unroll
        for (int k = 0; k < 8; ++k) {
            a[k]     += bf2f(u0[k]);
            a[k + 8] += bf2f(u1[k]);
        }
    }
    int deg = p1 - p0;
    float inv = 1.f / (float)(deg > 1 ? deg : 1);
    bf16x8 o0, o1;
#pragma unroll
    for (int k = 0; k < 8; ++k) {
        o0[k] = f2bf(a[k] * inv);
        o1[k] = f2bf(a[k + 8] * inv);
    }
    *(bf16x8*)(meanb + (size_t)node * 128 + qo) = o0;
    *(bf16x8*)(meanb + (size_t)node * 128 + qo + 8) = o1;
}

// ---------------- SAGE GEMM: out = relu?([mean|root] @ Wp + b), K=256, A all-bf16 ---
template <int NT, bool RELU, int MODE>
__global__ __launch_bounds__(256) void sage_gemm_kernel(
    const short* meanb, const short* root,
    const short* __restrict__ Wp, const float* __restrict__ b,
    void* outv, short* neb, int n) {
    int wave = (blockIdx.x * 256 + threadIdx.x) >> 6;
    int lane = threadIdx.x & 63;
    int rowbase = wave * 32;
    if (rowbase >= n) return;
    int g = lane >> 4, c = lane & 15;

    bf16x8 afrag[2][8];
#pragma unroll
    for (int s = 0; s < 2; ++s) {
        int i = rowbase + s * 16 + c;
        if (i >= n) i = n - 1;
        const short* mrow = meanb + (size_t)i * 128;
        const short* hrow = root + (size_t)i * 128;
#pragma unroll
        for (int ks = 0; ks < 4; ++ks) {
            afrag[s][ks]     = *(const bf16x8*)(mrow + ks * 32 + g * 8);
            afrag[s][ks + 4] = *(const bf16x8*)(hrow + ks * 32 + g * 8);
        }
    }

    f32x4 acc[2][NT];
    f32x4 z = {0.f, 0.f, 0.f, 0.f};
#pragma unroll
    for (int s = 0; s < 2; ++s)
#pragma unroll
        for (int ct = 0; ct < NT; ++ct) acc[s][ct] = z;

#pragma unroll
    for (int ct = 0; ct < NT; ++ct)
#pragma unroll
        for (int ks = 0; ks < 8; ++ks) {
            bf16x8 bfv = *(const bf16x8*)(Wp + ((size_t)(ct * 8 + ks) * 64 + lane) * 8);
            acc[0][ct] = __builtin_amdgcn_mfma_f32_16x16x32_bf16(afrag[0][ks], bfv, acc[0][ct], 0, 0, 0);
            acc[1][ct] = __builtin_amdgcn_mfma_f32_16x16x32_bf16(afrag[1][ks], bfv, acc[1][ct], 0, 0, 0);
        }

    const int N = NT * 16;
#pragma unroll
    for (int s = 0; s < 2; ++s)
#pragma unroll
        for (int ct = 0; ct < NT; ++ct)
#pragma unroll
            for (int r = 0; r < 4; ++r) {
                int row = rowbase + s * 16 + g * 4 + r;
                if (row < n) {
                    float v = acc[s][ct][r] + b[ct * 16 + c];
                    if (RELU) v = fmaxf(v, 0.f);
                    if (MODE == 0) {
                        ((short*)outv)[(size_t)row * N + ct * 16 + c] = f2bf(v);
                    } else {
                        ((float*)outv)[(size_t)row * N + ct * 16 + c] = v;
                        neb[(size_t)row * 128 + ct * 16 + c] = f2bf(v);
                    }
                }
            }
}

// ---------------- edge MLP, original-order fallback ----------------
__global__ __launch_bounds__(256) void edge_mlp_mfma_kernel(
    const short* __restrict__ neb, const int* __restrict__ src, const int* __restrict__ dst,
    const short* __restrict__ Wp, const float* __restrict__ bf1,
    const float* __restrict__ Wf2, const float* __restrict__ bf2,
    float* __restrict__ out, int nE) {
    int wave = (blockIdx.x * 256 + threadIdx.x) >> 6;
    int lane = threadIdx.x & 63;
    int rowbase = wave * 32;
    if (rowbase >= nE) return;
    int g = lane >> 4, c = lane & 15;

    bf16x8 afrag[2][4];
#pragma unroll
    for (int s = 0; s < 2; ++s) {
        int e = rowbase + s * 16 + c;
        const short* rs = neb + (size_t)src[e] * 128;
        const short* rd = neb + (size_t)dst[e] * 128;
        afrag[s][0] = *(const bf16x8*)(rs + g * 8);
        afrag[s][1] = *(const bf16x8*)(rs + 32 + g * 8);
        afrag[s][2] = *(const bf16x8*)(rd + g * 8);
        afrag[s][3] = *(const bf16x8*)(rd + 32 + g * 8);
    }

    f32x4 acc[2][8];
    f32x4 z = {0.f, 0.f, 0.f, 0.f};
#pragma unroll
    for (int s = 0; s < 2; ++s)
#pragma unroll
        for (int ct = 0; ct < 8; ++ct) acc[s][ct] = z;

#pragma unroll
    for (int ct = 0; ct < 8; ++ct)
#pragma unroll
        for (int ks = 0; ks < 4; ++ks) {
            bf16x8 bfv = *(const bf16x8*)(Wp + ((size_t)(ct * 4 + ks) * 64 + lane) * 8);
            acc[0][ct] = __builtin_amdgcn_mfma_f32_16x16x32_bf16(afrag[0][ks], bfv, acc[0][ct], 0, 0, 0);
            acc[1][ct] = __builtin_amdgcn_mfma_f32_16x16x32_bf16(afrag[1][ks], bfv, acc[1][ct], 0, 0, 0);
        }

    float bf1v[8], wf2v[8];
#pragma unroll
    for (int ct = 0; ct < 8; ++ct) {
        bf1v[ct] = bf1[ct * 16 + c];
        wf2v[ct] = Wf2[ct * 16 + c];
    }
    float bias2 = bf2[0];
#pragma unroll
    for (int s = 0; s < 2; ++s)
#pragma unroll
        for (int r = 0; r < 4; ++r) {
            float part = 0.f;
#pragma unroll
            for (int ct = 0; ct < 8; ++ct) {
                float hv = acc[s][ct][r] + bf1v[ct];
                hv = fmaxf(hv, 0.f);
                part = fmaf(hv, wf2v[ct], part);
            }
#pragma unroll
            for (int o = 1; o < 16; o <<= 1)
                part += __shfl_xor(part, o);
            if (c == 0) {
                int row = rowbase + s * 16 + g * 4 + r;
                out[row] = part + bias2;
            }
        }
}

// ---------------- edge MLP, dst-grouped (CSR position) order ----------------
// position p: src = col[p] (random gather), dst = edst[p] (runs of equal values,
// cache-hot), output scatters to out[eid[p]].
__global__ __launch_bounds__(256) void edge_mlp_sorted_kernel(
    const short* __restrict__ neb, const int* __restrict__ col,
    const unsigned short* __restrict__ edst, const int* __restrict__ eid,
    const short* __restrict__ Wp, const float* __restrict__ bf1,
    const float* __restrict__ Wf2, const float* __restrict__ bf2,
    float* __restrict__ out, int nE) {
    int wave = (blockIdx.x * 256 + threadIdx.x) >> 6;
    int lane = threadIdx.x & 63;
    int rowbase = wave * 32;
    if (rowbase >= nE) return;
    int g = lane >> 4, c = lane & 15;

    bf16x8 afrag[2][4];
#pragma unroll
    for (int s = 0; s < 2; ++s) {
        int p = rowbase + s * 16 + c;
        const short* rs = neb + (size_t)col[p] * 128;
        const short* rd = neb + (size_t)edst[p] * 128;
        afrag[s][0] = *(const bf16x8*)(rs + g * 8);
        afrag[s][1] = *(const bf16x8*)(rs + 32 + g * 8);
        afrag[s][2] = *(const bf16x8*)(rd + g * 8);
        afrag[s][3] = *(const bf16x8*)(rd + 32 + g * 8);
    }

    f32x4 acc[2][8];
    f32x4 z = {0.f, 0.f, 0.f, 0.f};
#pragma unroll
    for (int s = 0; s < 2; ++s)
#pragma unroll
        for (int ct = 0; ct < 8; ++ct) acc[s][ct] = z;

#pragma unroll
    for (int ct = 0; ct < 8; ++ct)
#pragma unroll
        for (int ks = 0; ks < 4; ++ks) {
            bf16x8 bfv = *(const bf16x8*)(Wp + ((size_t)(ct * 4 + ks) * 64 + lane) * 8);
            acc[0][ct] = __builtin_amdgcn_mfma_f32_16x16x32_bf16(afrag[0][ks], bfv, acc[0][ct], 0, 0, 0);
            acc[1][ct] = __builtin_amdgcn_mfma_f32_16x16x32_bf16(afrag[1][ks], bfv, acc[1][ct], 0, 0, 0);
        }

    float bf1v[8], wf2v[8];
#pragma unroll
    for (int ct = 0; ct < 8; ++ct) {
        bf1v[ct] = bf1[ct * 16 + c];
        wf2v[ct] = Wf2[ct * 16 + c];
    }
    float bias2 = bf2[0];
#pragma unroll
    for (int s = 0; s < 2; ++s)
#pragma unroll
        for (int r = 0; r < 4; ++r) {
            float part = 0.f;
#pragma unroll
            for (int ct = 0; ct < 8; ++ct) {
                float hv = acc[s][ct][r] + bf1v[ct];
                hv = fmaxf(hv, 0.f);
                part = fmaf(hv, wf2v[ct], part);
            }
#pragma unroll
            for (int o = 1; o < 16; o <<= 1)
                part += __shfl_xor(part, o);
            if (c == 0) {
                int row = rowbase + s * 16 + g * 4 + r;
                out[eid[row]] = part + bias2;
            }
        }
}

// ---------------- classifier: ne @ Wc + bc ----------------
__global__ __launch_bounds__(64, 2) void classifier_kernel(
    const float* __restrict__ ne, const float* __restrict__ Wc,
    const float* __restrict__ bc, float* __restrict__ out, int n) {
    int i = blockIdx.x * 64 + threadIdx.x;
    if (i >= n) return;
    float v[64];
    const float4* r = (const float4*)(ne + (size_t)i * 64);
#pragma unroll
    for (int j = 0; j < 16; ++j) {
        float4 q = r[j];
        v[4 * j + 0] = q.x; v[4 * j + 1] = q.y; v[4 * j + 2] = q.z; v[4 * j + 3] = q.w;
    }
#pragma unroll
    for (int cidx = 0; cidx < 4; ++cidx) {
        float a0 = 0.f, a1 = 0.f, a2 = 0.f, a3 = 0.f;
#pragma unroll
        for (int k = 0; k < 64; k += 4) {
            a0 = fmaf(v[k + 0], Wc[(k + 0) * 4 + cidx], a0);
            a1 = fmaf(v[k + 1], Wc[(k + 1) * 4 + cidx], a1);
            a2 = fmaf(v[k + 2], Wc[(k + 2) * 4 + cidx], a2);
            a3 = fmaf(v[k + 3], Wc[(k + 3) * 4 + cidx], a3);
        }
        out[(size_t)i * 4 + cidx] = bc[cidx] + (a0 + a1) + (a2 + a3);
    }
}

extern "C" void kernel_launch(void* const* d_in, const int* in_sizes, int n_in,
                              void* d_out, int out_size, void* d_ws, size_t ws_size,
                              hipStream_t stream) {
    const float* x   = (const float*)d_in[0];
    const int*   ei  = (const int*)d_in[1];
    const int*   src = ei;
    const int*   dst = ei + NE;
    const float* Wl0 = (const float*)d_in[2];
    const float* Wr0 = (const float*)d_in[3];
    const float* b0  = (const float*)d_in[4];
    const float* Wl1 = (const float*)d_in[5];
    const float* Wr1 = (const float*)d_in[6];
    const float* b1  = (const float*)d_in[7];
    const float* Wl2 = (const float*)d_in[8];
    const float* Wr2 = (const float*)d_in[9];
    const float* b2  = (const float*)d_in[10];
    const float* Wf1 = (const float*)d_in[11];
    const float* bf1 = (const float*)d_in[12];
    const float* Wf2 = (const float*)d_in[13];
    const float* bf2 = (const float*)d_in[14];
    const float* Wc  = (const float*)d_in[15];
    const float* bc  = (const float*)d_in[16];

    // ---- workspace carve-up (base ~29.4 MiB; +4.8 MiB for sorted-edge path) ----
    short* sp = (short*)d_ws;
    short* W0p = sp; sp += 256 * 128;
    short* W1p = sp; sp += 256 * 128;
    short* W2p = sp; sp += 256 * 64;
    short* Wfp = sp; sp += 128 * 128;
    short* meanb = sp; sp += (size_t)NN * 128;   // mean rows; layer2 also packs neb here
    short* hb    = sp; sp += (size_t)NN * 128;   // xb -> h1 -> h2 (aliased, in-place)
    int* ip = (int*)sp;
    int* off    = ip; ip += 50008;
    int* cursor = ip; ip += 50000;               // also deg
    int* col    = ip; ip += 800000;
    int* bsum   = ip; ip += 256;

    const bool sorted = ws_size >= (size_t)36 * 1024 * 1024;
    int* eid = nullptr;
    unsigned short* edst = nullptr;
    if (sorted) {
        eid  = ip; ip += NE;                     // 3.2 MB
        edst = (unsigned short*)ip; ip += NE / 2; // 1.6 MB
    }

    float* ne = (float*)d_out;               // [NN,64]
    float* cf = ne + (size_t)NN * 64;        // [NE]
    float* sc = cf + NE;                     // [NN,4]

    int* deg = cursor;
    const int NB = (NN + 255) / 256;

    // --- CSR build ---
    hipMemsetAsync(deg, 0, NN * sizeof(int), stream);
    count_deg_kernel<<<(NE + 255) / 256, 256, 0, stream>>>(dst, deg, NE);
    scan1_kernel<<<NB, 256, 0, stream>>>(deg, off, bsum, NN);
    scan2_kernel<<<1, 256, 0, stream>>>(bsum, NB);
    scan3_kernel<<<NB, 256, 0, stream>>>(off, bsum, cursor, NN, NE);
    fill_kernel<<<(NE + 255) / 256, 256, 0, stream>>>(src, dst, cursor, col, eid, NE);
    if (sorted)
        edst_fill_kernel<<<NB, 256, 0, stream>>>(off, edst, NN);

    // --- x -> bf16 (into hb region), weight packs ---
    cvt_bf16_kernel<<<(NN * 16 + 255) / 256, 256, 0, stream>>>(x, hb, NN * 16);
    pack_b_kernel<<<(4096 + 255) / 256, 256, 0, stream>>>(Wl0, Wr0, 128, 256, 128, W0p);
    pack_b_kernel<<<(4096 + 255) / 256, 256, 0, stream>>>(Wl1, Wr1, 128, 256, 128, W1p);
    pack_b_kernel<<<(2048 + 255) / 256, 256, 0, stream>>>(Wl2, Wr2, 128, 256, 64, W2p);
    pack_b_kernel<<<(2048 + 255) / 256, 256, 0, stream>>>(Wf1, Wf1, 128, 128, 128, Wfp);

    int agrid = (NN * 8 + 255) / 256;
    int sgrid = ((NN + 31) / 32 + 3) / 4;
    int egrid = (NE / 32) / 4;

    // --- layer 0 ---
    agg_mean_kernel<<<agrid, 256, 0, stream>>>(hb, off, col, meanb, NN);
    sage_gemm_kernel<8, true, 0><<<sgrid, 256, 0, stream>>>(meanb, hb, W0p, b0, hb, nullptr, NN);
    // --- layer 1 ---
    agg_mean_kernel<<<agrid, 256, 0, stream>>>(hb, off, col, meanb, NN);
    sage_gemm_kernel<8, true, 0><<<sgrid, 256, 0, stream>>>(meanb, hb, W1p, b1, hb, nullptr, NN);
    // --- layer 2 -> ne (f32, d_out) + neb (bf16, into meanb slots) ---
    agg_mean_kernel<<<agrid, 256, 0, stream>>>(hb, off, col, meanb, NN);
    sage_gemm_kernel<4, false, 1><<<sgrid, 256, 0, stream>>>(meanb, hb, W2p, b2, ne, meanb, NN);

    // --- heads ---
    if (sorted)
        edge_mlp_sorted_kernel<<<egrid, 256, 0, stream>>>(meanb, col, edst, eid, Wfp, bf1, Wf2, bf2, cf, NE);
    else
        edge_mlp_mfma_kernel<<<egrid, 256, 0, stream>>>(meanb, src, dst, Wfp, bf1, Wf2, bf2, cf, NE);
    classifier_kernel<<<(NN + 63) / 64, 64, 0, stream>>>(ne, Wc, bc, sc, NN);
}

// Round 6
// 350.791 us; speedup vs baseline: 1.0240x; 1.0240x over previous
//
#include <hip/hip_runtime.h>

#define NN 50000
#define NE 800000

typedef __attribute__((ext_vector_type(8))) short bf16x8;
typedef __attribute__((ext_vector_type(4))) float f32x4;

__device__ inline short f2bf(float f) {
    union { float f; unsigned u; } v; v.f = f;
    unsigned r = v.u + 0x7fffu + ((v.u >> 16) & 1u);
    return (short)(r >> 16);
}
__device__ inline float bf2f(short s) {
    union { unsigned u; float f; } v;
    v.u = ((unsigned)(unsigned short)s) << 16;
    return v.f;
}

// ---------------- CSR build ----------------
__global__ __launch_bounds__(256) void count_deg_kernel(const int* __restrict__ dst,
                                                        int* __restrict__ deg, int n) {
    int e = blockIdx.x * 256 + threadIdx.x;
    if (e < n) atomicAdd(&deg[dst[e]], 1);
}

__global__ __launch_bounds__(256) void scan1_kernel(const int* __restrict__ deg,
                                                    int* __restrict__ off,
                                                    int* __restrict__ bsum, int n) {
    __shared__ int s[256];
    int t = threadIdx.x;
    int i = blockIdx.x * 256 + t;
    int v = (i < n) ? deg[i] : 0;
    s[t] = v;
    __syncthreads();
    for (int d = 1; d < 256; d <<= 1) {
        int u = (t >= d) ? s[t - d] : 0;
        __syncthreads();
        s[t] += u;
        __syncthreads();
    }
    if (i < n) off[i] = s[t] - v;
    if (t == 255) bsum[blockIdx.x] = s[255];
}

__global__ __launch_bounds__(256) void scan2_kernel(int* __restrict__ bsum, int nb) {
    __shared__ int s[256];
    int t = threadIdx.x;
    int v = (t < nb) ? bsum[t] : 0;
    s[t] = v;
    __syncthreads();
    for (int d = 1; d < 256; d <<= 1) {
        int u = (t >= d) ? s[t - d] : 0;
        __syncthreads();
        s[t] += u;
        __syncthreads();
    }
    if (t < nb) bsum[t] = s[t] - v;
}

__global__ __launch_bounds__(256) void scan3_kernel(int* __restrict__ off,
                                                    const int* __restrict__ bsum,
                                                    int* __restrict__ cursor, int n, int total) {
    int i = blockIdx.x * 256 + threadIdx.x;
    if (i < n) {
        int v = off[i] + bsum[i >> 8];
        off[i] = v;
        cursor[i] = v;
    }
    if (i == 0) off[n] = total;
}

__global__ __launch_bounds__(256) void fill_kernel(const int* __restrict__ src,
                                                   const int* __restrict__ dst,
                                                   int* __restrict__ cursor,
                                                   int* __restrict__ col, int n) {
    int e = blockIdx.x * 256 + threadIdx.x;
    if (e < n) {
        int p = atomicAdd(&cursor[dst[e]], 1);
        col[p] = src[e];
    }
}

// ---------------- f32 -> bf16 convert (8 elems/thread) ----------------
__global__ __launch_bounds__(256) void cvt_bf16_kernel(const float* __restrict__ in,
                                                       short* __restrict__ outb, int n8) {
    int t = blockIdx.x * 256 + threadIdx.x;
    if (t >= n8) return;
    const float4* p = (const float4*)(in + (size_t)t * 8);
    float4 v0 = p[0], v1 = p[1];
    bf16x8 o;
    o[0] = f2bf(v0.x); o[1] = f2bf(v0.y); o[2] = f2bf(v0.z); o[3] = f2bf(v0.w);
    o[4] = f2bf(v1.x); o[5] = f2bf(v1.y); o[6] = f2bf(v1.z); o[7] = f2bf(v1.w);
    *(bf16x8*)(outb + (size_t)t * 8) = o;
}

// ---------------- pack B = [B0;B1] (f32 row-major, K x N) into bf16 MFMA fragments ----
__global__ __launch_bounds__(256) void pack_b_kernel(
    const float* __restrict__ B0, const float* __restrict__ B1,
    int K0, int K, int N, short* __restrict__ out) {
    int t = blockIdx.x * 256 + threadIdx.x;
    int total = (N >> 4) * (K >> 5) * 64;
    if (t >= total) return;
    int l = t & 63;
    int fs = t >> 6;
    int KS = K >> 5;
    int ct = fs / KS, ks = fs - ct * KS;
    int coln = ct * 16 + (l & 15);
    int k0 = ks * 32 + (l >> 4) * 8;
    bf16x8 v;
#pragma unroll
    for (int j = 0; j < 8; ++j) {
        int k = k0 + j;
        float f = (k < K0) ? B0[(size_t)k * N + coln] : B1[(size_t)(k - K0) * N + coln];
        v[j] = f2bf(f);
    }
    *(bf16x8*)(out + (size_t)t * 8) = v;
}

// ------------- mean aggregation: 16 lanes/node, 8 cols/lane, 4 rows in flight -------
// low-VGPR (~40) so 8 waves/SIMD can be resident to hide gather latency
__global__ __launch_bounds__(256) void agg_mean_kernel(
    const short* __restrict__ hbase, const int* __restrict__ off,
    const int* __restrict__ col, short* __restrict__ meanb, int n) {
    int t = blockIdx.x * 256 + threadIdx.x;
    int node = t >> 4, q = t & 15;
    if (node >= n) return;
    int p0 = off[node], p1 = off[node + 1];
    float a[8];
#pragma unroll
    for (int k = 0; k < 8; ++k) a[k] = 0.f;
    int qo = q * 8;
    int p = p0;
    for (; p + 3 < p1; p += 4) {
        int c0 = col[p], c1 = col[p + 1], c2 = col[p + 2], c3 = col[p + 3];
        bf16x8 u0 = *(const bf16x8*)(hbase + (size_t)c0 * 128 + qo);
        bf16x8 u1 = *(const bf16x8*)(hbase + (size_t)c1 * 128 + qo);
        bf16x8 u2 = *(const bf16x8*)(hbase + (size_t)c2 * 128 + qo);
        bf16x8 u3 = *(const bf16x8*)(hbase + (size_t)c3 * 128 + qo);
#pragma unroll
        for (int k = 0; k < 8; ++k)
            a[k] += (bf2f(u0[k]) + bf2f(u1[k])) + (bf2f(u2[k]) + bf2f(u3[k]));
    }
    for (; p < p1; ++p) {
        bf16x8 u0 = *(const bf16x8*)(hbase + (size_t)col[p] * 128 + qo);
#pragma unroll
        for (int k = 0; k < 8; ++k) a[k] += bf2f(u0[k]);
    }
    int deg = p1 - p0;
    float inv = 1.f / (float)(deg > 1 ? deg : 1);
    bf16x8 o;
#pragma unroll
    for (int k = 0; k < 8; ++k) o[k] = f2bf(a[k] * inv);
    *(bf16x8*)(meanb + (size_t)node * 128 + qo) = o;
}

// ---------------- SAGE GEMM: out = relu?([mean|root] @ Wp + b), K=256, A all-bf16 ---
// MODE 0: bf16 out [n, NT*16];  MODE 1: f32 out [n,64] + compact bf16 neb [n,64]
template <int NT, bool RELU, int MODE>
__global__ __launch_bounds__(256) void sage_gemm_kernel(
    const short* meanb, const short* root,
    const short* __restrict__ Wp, const float* __restrict__ b,
    void* outv, short* neb, int n) {
    int wave = (blockIdx.x * 256 + threadIdx.x) >> 6;
    int lane = threadIdx.x & 63;
    int rowbase = wave * 32;
    if (rowbase >= n) return;
    int g = lane >> 4, c = lane & 15;

    bf16x8 afrag[2][8];
#pragma unroll
    for (int s = 0; s < 2; ++s) {
        int i = rowbase + s * 16 + c;
        if (i >= n) i = n - 1;
        const short* mrow = meanb + (size_t)i * 128;
        const short* hrow = root + (size_t)i * 128;
#pragma unroll
        for (int ks = 0; ks < 4; ++ks) {
            afrag[s][ks]     = *(const bf16x8*)(mrow + ks * 32 + g * 8);
            afrag[s][ks + 4] = *(const bf16x8*)(hrow + ks * 32 + g * 8);
        }
    }

    f32x4 acc[2][NT];
    f32x4 z = {0.f, 0.f, 0.f, 0.f};
#pragma unroll
    for (int s = 0; s < 2; ++s)
#pragma unroll
        for (int ct = 0; ct < NT; ++ct) acc[s][ct] = z;

#pragma unroll
    for (int ct = 0; ct < NT; ++ct)
#pragma unroll
        for (int ks = 0; ks < 8; ++ks) {
            bf16x8 bfv = *(const bf16x8*)(Wp + ((size_t)(ct * 8 + ks) * 64 + lane) * 8);
            acc[0][ct] = __builtin_amdgcn_mfma_f32_16x16x32_bf16(afrag[0][ks], bfv, acc[0][ct], 0, 0, 0);
            acc[1][ct] = __builtin_amdgcn_mfma_f32_16x16x32_bf16(afrag[1][ks], bfv, acc[1][ct], 0, 0, 0);
        }

    const int N = NT * 16;
#pragma unroll
    for (int s = 0; s < 2; ++s)
#pragma unroll
        for (int ct = 0; ct < NT; ++ct)
#pragma unroll
            for (int r = 0; r < 4; ++r) {
                int row = rowbase + s * 16 + g * 4 + r;
                if (row < n) {
                    float v = acc[s][ct][r] + b[ct * 16 + c];
                    if (RELU) v = fmaxf(v, 0.f);
                    if (MODE == 0) {
                        ((short*)outv)[(size_t)row * N + ct * 16 + c] = f2bf(v);
                    } else {
                        ((float*)outv)[(size_t)row * N + ct * 16 + c] = v;
                        neb[(size_t)row * 64 + ct * 16 + c] = f2bf(v);
                    }
                }
            }
}

// ---------------- edge MLP: 16 edges/wave, low-register for occupancy ----------------
// relu([neb[src]|neb[dst]] @ Wfp + bf1) . Wf2 + bf2;  neb compact [NN,64] bf16
__global__ __launch_bounds__(256) void edge_mlp16_kernel(
    const short* __restrict__ neb, const int* __restrict__ src, const int* __restrict__ dst,
    const short* __restrict__ Wp, const float* __restrict__ bf1,
    const float* __restrict__ Wf2, const float* __restrict__ bf2,
    float* __restrict__ out, int nE) {
    int wave = (blockIdx.x * 256 + threadIdx.x) >> 6;
    int lane = threadIdx.x & 63;
    int rowbase = wave * 16;
    if (rowbase >= nE) return;
    int g = lane >> 4, c = lane & 15;

    int e = rowbase + c;
    const short* rs = neb + (size_t)src[e] * 64;
    const short* rd = neb + (size_t)dst[e] * 64;
    bf16x8 a0 = *(const bf16x8*)(rs + g * 8);
    bf16x8 a1 = *(const bf16x8*)(rs + 32 + g * 8);
    bf16x8 a2 = *(const bf16x8*)(rd + g * 8);
    bf16x8 a3 = *(const bf16x8*)(rd + 32 + g * 8);

    f32x4 acc[8];
    f32x4 z = {0.f, 0.f, 0.f, 0.f};
#pragma unroll
    for (int ct = 0; ct < 8; ++ct) acc[ct] = z;

#pragma unroll
    for (int ct = 0; ct < 8; ++ct) {
        acc[ct] = __builtin_amdgcn_mfma_f32_16x16x32_bf16(a0, *(const bf16x8*)(Wp + ((size_t)(ct * 4 + 0) * 64 + lane) * 8), acc[ct], 0, 0, 0);
        acc[ct] = __builtin_amdgcn_mfma_f32_16x16x32_bf16(a1, *(const bf16x8*)(Wp + ((size_t)(ct * 4 + 1) * 64 + lane) * 8), acc[ct], 0, 0, 0);
        acc[ct] = __builtin_amdgcn_mfma_f32_16x16x32_bf16(a2, *(const bf16x8*)(Wp + ((size_t)(ct * 4 + 2) * 64 + lane) * 8), acc[ct], 0, 0, 0);
        acc[ct] = __builtin_amdgcn_mfma_f32_16x16x32_bf16(a3, *(const bf16x8*)(Wp + ((size_t)(ct * 4 + 3) * 64 + lane) * 8), acc[ct], 0, 0, 0);
    }

    float bf1v[8], wf2v[8];
#pragma unroll
    for (int ct = 0; ct < 8; ++ct) {
        bf1v[ct] = bf1[ct * 16 + c];
        wf2v[ct] = Wf2[ct * 16 + c];
    }
    float bias2 = bf2[0];
#pragma unroll
    for (int r = 0; r < 4; ++r) {
        float part = 0.f;
#pragma unroll
        for (int ct = 0; ct < 8; ++ct) {
            float hv = acc[ct][r] + bf1v[ct];
            hv = fmaxf(hv, 0.f);
            part = fmaf(hv, wf2v[ct], part);
        }
#pragma unroll
        for (int o = 1; o < 16; o <<= 1)
            part += __shfl_xor(part, o);
        if (c == 0) {
            int row = rowbase + g * 4 + r;
            out[row] = part + bias2;
        }
    }
}

// ---------------- classifier: neb(bf16 compact) @ Wc + bc ----------------
__global__ __launch_bounds__(64, 2) void classifier_kernel(
    const short* __restrict__ neb, const float* __restrict__ Wc,
    const float* __restrict__ bc, float* __restrict__ out, int n) {
    int i = blockIdx.x * 64 + threadIdx.x;
    if (i >= n) return;
    const short* row = neb + (size_t)i * 64;
    bf16x8 r[8];
#pragma unroll
    for (int j = 0; j < 8; ++j) r[j] = *(const bf16x8*)(row + j * 8);
#pragma unroll
    for (int cidx = 0; cidx < 4; ++cidx) {
        float a0 = 0.f, a1 = 0.f, a2 = 0.f, a3 = 0.f;
#pragma unroll
        for (int j = 0; j < 8; ++j) {
            a0 = fmaf(bf2f(r[j][0]), Wc[(j * 8 + 0) * 4 + cidx], a0);
            a1 = fmaf(bf2f(r[j][1]), Wc[(j * 8 + 1) * 4 + cidx], a1);
            a2 = fmaf(bf2f(r[j][2]), Wc[(j * 8 + 2) * 4 + cidx], a2);
            a3 = fmaf(bf2f(r[j][3]), Wc[(j * 8 + 3) * 4 + cidx], a3);
            a0 = fmaf(bf2f(r[j][4]), Wc[(j * 8 + 4) * 4 + cidx], a0);
            a1 = fmaf(bf2f(r[j][5]), Wc[(j * 8 + 5) * 4 + cidx], a1);
            a2 = fmaf(bf2f(r[j][6]), Wc[(j * 8 + 6) * 4 + cidx], a2);
            a3 = fmaf(bf2f(r[j][7]), Wc[(j * 8 + 7) * 4 + cidx], a3);
        }
        out[(size_t)i * 4 + cidx] = bc[cidx] + (a0 + a1) + (a2 + a3);
    }
}

extern "C" void kernel_launch(void* const* d_in, const int* in_sizes, int n_in,
                              void* d_out, int out_size, void* d_ws, size_t ws_size,
                              hipStream_t stream) {
    const float* x   = (const float*)d_in[0];
    const int*   ei  = (const int*)d_in[1];
    const int*   src = ei;
    const int*   dst = ei + NE;
    const float* Wl0 = (const float*)d_in[2];
    const float* Wr0 = (const float*)d_in[3];
    const float* b0  = (const float*)d_in[4];
    const float* Wl1 = (const float*)d_in[5];
    const float* Wr1 = (const float*)d_in[6];
    const float* b1  = (const float*)d_in[7];
    const float* Wl2 = (const float*)d_in[8];
    const float* Wr2 = (const float*)d_in[9];
    const float* b2  = (const float*)d_in[10];
    const float* Wf1 = (const float*)d_in[11];
    const float* bf1 = (const float*)d_in[12];
    const float* Wf2 = (const float*)d_in[13];
    const float* bf2 = (const float*)d_in[14];
    const float* Wc  = (const float*)d_in[15];
    const float* bc  = (const float*)d_in[16];

    // ---- workspace carve-up (~34.1 MiB; 36 MiB proven available in R5) ----
    short* sp = (short*)d_ws;
    short* W0p = sp; sp += 256 * 128;
    short* W1p = sp; sp += 256 * 128;
    short* W2p = sp; sp += 256 * 64;
    short* Wfp = sp; sp += 128 * 128;
    short* meanb = sp; sp += (size_t)NN * 128;   // bf16 mean rows, stride 128
    short* hb    = sp; sp += (size_t)NN * 128;   // xb -> h1 -> h2 (in-place)
    short* neb   = sp; sp += (size_t)NN * 64;    // compact bf16 node embeddings
    int* ip = (int*)sp;
    int* off    = ip; ip += 50008;
    int* cursor = ip; ip += 50000;               // also deg
    int* col    = ip; ip += 800000;
    int* bsum   = ip; ip += 256;

    float* ne = (float*)d_out;               // [NN,64]
    float* cf = ne + (size_t)NN * 64;        // [NE]
    float* sc = cf + NE;                     // [NN,4]

    int* deg = cursor;
    const int NB = (NN + 255) / 256;

    // --- CSR build ---
    hipMemsetAsync(deg, 0, NN * sizeof(int), stream);
    count_deg_kernel<<<(NE + 255) / 256, 256, 0, stream>>>(dst, deg, NE);
    scan1_kernel<<<NB, 256, 0, stream>>>(deg, off, bsum, NN);
    scan2_kernel<<<1, 256, 0, stream>>>(bsum, NB);
    scan3_kernel<<<NB, 256, 0, stream>>>(off, bsum, cursor, NN, NE);
    fill_kernel<<<(NE + 255) / 256, 256, 0, stream>>>(src, dst, cursor, col, NE);

    // --- x -> bf16 (into hb region), weight packs ---
    cvt_bf16_kernel<<<(NN * 16 + 255) / 256, 256, 0, stream>>>(x, hb, NN * 16);
    pack_b_kernel<<<(4096 + 255) / 256, 256, 0, stream>>>(Wl0, Wr0, 128, 256, 128, W0p);
    pack_b_kernel<<<(4096 + 255) / 256, 256, 0, stream>>>(Wl1, Wr1, 128, 256, 128, W1p);
    pack_b_kernel<<<(2048 + 255) / 256, 256, 0, stream>>>(Wl2, Wr2, 128, 256, 64, W2p);
    pack_b_kernel<<<(2048 + 255) / 256, 256, 0, stream>>>(Wf1, Wf1, 128, 128, 128, Wfp);

    int agrid = (NN * 16 + 255) / 256;          // 3125
    int sgrid = ((NN + 31) / 32 + 3) / 4;       // 391
    int egrid = (NE / 16 + 3) / 4;              // 12500

    // --- layer 0 ---
    agg_mean_kernel<<<agrid, 256, 0, stream>>>(hb, off, col, meanb, NN);
    sage_gemm_kernel<8, true, 0><<<sgrid, 256, 0, stream>>>(meanb, hb, W0p, b0, hb, nullptr, NN);
    // --- layer 1 ---
    agg_mean_kernel<<<agrid, 256, 0, stream>>>(hb, off, col, meanb, NN);
    sage_gemm_kernel<8, true, 0><<<sgrid, 256, 0, stream>>>(meanb, hb, W1p, b1, hb, nullptr, NN);
    // --- layer 2 -> ne (f32, d_out) + neb (compact bf16) ---
    agg_mean_kernel<<<agrid, 256, 0, stream>>>(hb, off, col, meanb, NN);
    sage_gemm_kernel<4, false, 1><<<sgrid, 256, 0, stream>>>(meanb, hb, W2p, b2, ne, neb, NN);

    // --- heads ---
    edge_mlp16_kernel<<<egrid, 256, 0, stream>>>(neb, src, dst, Wfp, bf1, Wf2, bf2, cf, NE);
    classifier_kernel<<<(NN + 63) / 64, 64, 0, stream>>>(neb, Wc, bc, sc, NN);
}

// Round 7
// 323.316 us; speedup vs baseline: 1.1110x; 1.0850x over previous
//
#include <hip/hip_runtime.h>

#define NN 50000
#define NE 800000

typedef __attribute__((ext_vector_type(8))) short bf16x8;
typedef __attribute__((ext_vector_type(4))) float f32x4;

__device__ inline short f2bf(float f) {
    union { float f; unsigned u; } v; v.f = f;
    unsigned r = v.u + 0x7fffu + ((v.u >> 16) & 1u);
    return (short)(r >> 16);
}
__device__ inline float bf2f(short s) {
    union { unsigned u; float f; } v;
    v.u = ((unsigned)(unsigned short)s) << 16;
    return v.f;
}

// ---------------- CSR build ----------------
__global__ __launch_bounds__(256) void count_deg_kernel(const int* __restrict__ dst,
                                                        int* __restrict__ deg, int n) {
    int e = blockIdx.x * 256 + threadIdx.x;
    if (e < n) atomicAdd(&deg[dst[e]], 1);
}

__global__ __launch_bounds__(256) void scan1_kernel(const int* __restrict__ deg,
                                                    int* __restrict__ off,
                                                    int* __restrict__ bsum, int n) {
    __shared__ int s[256];
    int t = threadIdx.x;
    int i = blockIdx.x * 256 + t;
    int v = (i < n) ? deg[i] : 0;
    s[t] = v;
    __syncthreads();
    for (int d = 1; d < 256; d <<= 1) {
        int u = (t >= d) ? s[t - d] : 0;
        __syncthreads();
        s[t] += u;
        __syncthreads();
    }
    if (i < n) off[i] = s[t] - v;
    if (t == 255) bsum[blockIdx.x] = s[255];
}

__global__ __launch_bounds__(256) void scan2_kernel(int* __restrict__ bsum, int nb) {
    __shared__ int s[256];
    int t = threadIdx.x;
    int v = (t < nb) ? bsum[t] : 0;
    s[t] = v;
    __syncthreads();
    for (int d = 1; d < 256; d <<= 1) {
        int u = (t >= d) ? s[t - d] : 0;
        __syncthreads();
        s[t] += u;
        __syncthreads();
    }
    if (t < nb) bsum[t] = s[t] - v;
}

__global__ __launch_bounds__(256) void scan3_kernel(int* __restrict__ off,
                                                    const int* __restrict__ bsum,
                                                    int* __restrict__ cursor, int n, int total) {
    int i = blockIdx.x * 256 + threadIdx.x;
    if (i < n) {
        int v = off[i] + bsum[i >> 8];
        off[i] = v;
        cursor[i] = v;
    }
    if (i == 0) off[n] = total;
}

__global__ __launch_bounds__(256) void fill_kernel(const int* __restrict__ src,
                                                   const int* __restrict__ dst,
                                                   int* __restrict__ cursor,
                                                   int* __restrict__ col, int n) {
    int e = blockIdx.x * 256 + threadIdx.x;
    if (e < n) {
        int p = atomicAdd(&cursor[dst[e]], 1);
        col[p] = src[e];
    }
}

// ---------------- f32 -> bf16 convert (8 elems/thread) ----------------
__global__ __launch_bounds__(256) void cvt_bf16_kernel(const float* __restrict__ in,
                                                       short* __restrict__ outb, int n8) {
    int t = blockIdx.x * 256 + threadIdx.x;
    if (t >= n8) return;
    const float4* p = (const float4*)(in + (size_t)t * 8);
    float4 v0 = p[0], v1 = p[1];
    bf16x8 o;
    o[0] = f2bf(v0.x); o[1] = f2bf(v0.y); o[2] = f2bf(v0.z); o[3] = f2bf(v0.w);
    o[4] = f2bf(v1.x); o[5] = f2bf(v1.y); o[6] = f2bf(v1.z); o[7] = f2bf(v1.w);
    *(bf16x8*)(outb + (size_t)t * 8) = o;
}

// ---------------- pack one f32 KxN matrix into bf16 MFMA B-fragments --------------
// frag index fs = ct*(K/32)+ks, lane l, elem j: out[(fs*64+l)*8+j] = B[ks*32+(l>>4)*8+j][ct*16+(l&15)]
__device__ inline void pack_one(const float* B, int K, int N, short* out, int t) {
    int l = t & 63;
    int fs = t >> 6;
    int KS = K >> 5;
    int ct = fs / KS, ks = fs - ct * KS;
    int coln = ct * 16 + (l & 15);
    int k0 = ks * 32 + (l >> 4) * 8;
    bf16x8 v;
#pragma unroll
    for (int j = 0; j < 8; ++j)
        v[j] = f2bf(B[(size_t)(k0 + j) * N + coln]);
    *(bf16x8*)(out + (size_t)t * 8) = v;
}

// all 7 weight packs in one dispatch
__global__ __launch_bounds__(256) void pack_all_kernel(
    const float* __restrict__ Wl0, const float* __restrict__ Wr0,
    const float* __restrict__ Wl1, const float* __restrict__ Wr1,
    const float* __restrict__ Wl2, const float* __restrict__ Wr2,
    const float* __restrict__ Wf1,
    short* W0lp, short* W0rp, short* W1lp, short* W1rp,
    short* W2lp, short* W2rp, short* Wfp) {
    int t = blockIdx.x * 256 + threadIdx.x;
    if (t < 2048)              pack_one(Wl0, 128, 128, W0lp, t);
    else if (t < 4096)         pack_one(Wr0, 128, 128, W0rp, t - 2048);
    else if (t < 6144)         pack_one(Wl1, 128, 128, W1lp, t - 4096);
    else if (t < 8192)         pack_one(Wr1, 128, 128, W1rp, t - 6144);
    else if (t < 9216)         pack_one(Wl2, 128, 64,  W2lp, t - 8192);
    else if (t < 10240)        pack_one(Wr2, 128, 64,  W2rp, t - 9216);
    else if (t < 12288)        pack_one(Wf1, 128, 128, Wfp,  t - 10240);
}

// ---------------- transform GEMM: g = h@Wl ; r = h@Wr + b  (K=128) ----------------
// h rows stride 128 (bf16). g written bf16 stride NT*16. r written bf16 stride 128
// IN-PLACE over h rows (row-private: afrag held in regs before stores).
template <int NT>
__global__ __launch_bounds__(256) void gemm_tf_kernel(
    const short* hb, const short* __restrict__ Wlp, const short* __restrict__ Wrp,
    const float* __restrict__ b, short* g, short* r, int n) {
    int wave = (blockIdx.x * 256 + threadIdx.x) >> 6;
    int lane = threadIdx.x & 63;
    int rowbase = wave * 32;
    if (rowbase >= n) return;
    int gq = lane >> 4, c = lane & 15;

    bf16x8 afrag[2][4];
#pragma unroll
    for (int s = 0; s < 2; ++s) {
        int i = rowbase + s * 16 + c;
        if (i >= n) i = n - 1;
        const short* hr = hb + (size_t)i * 128;
#pragma unroll
        for (int ks = 0; ks < 4; ++ks)
            afrag[s][ks] = *(const bf16x8*)(hr + ks * 32 + gq * 8);
    }

    f32x4 acc[2][NT];
    f32x4 z = {0.f, 0.f, 0.f, 0.f};

    // ---- phase 1: g = h @ Wl ----
#pragma unroll
    for (int s = 0; s < 2; ++s)
#pragma unroll
        for (int ct = 0; ct < NT; ++ct) acc[s][ct] = z;
#pragma unroll
    for (int ct = 0; ct < NT; ++ct)
#pragma unroll
        for (int ks = 0; ks < 4; ++ks) {
            bf16x8 bfv = *(const bf16x8*)(Wlp + ((size_t)(ct * 4 + ks) * 64 + lane) * 8);
            acc[0][ct] = __builtin_amdgcn_mfma_f32_16x16x32_bf16(afrag[0][ks], bfv, acc[0][ct], 0, 0, 0);
            acc[1][ct] = __builtin_amdgcn_mfma_f32_16x16x32_bf16(afrag[1][ks], bfv, acc[1][ct], 0, 0, 0);
        }
    const int NG = NT * 16;
#pragma unroll
    for (int s = 0; s < 2; ++s)
#pragma unroll
        for (int ct = 0; ct < NT; ++ct)
#pragma unroll
            for (int rr = 0; rr < 4; ++rr) {
                int row = rowbase + s * 16 + gq * 4 + rr;
                if (row < n)
                    g[(size_t)row * NG + ct * 16 + c] = f2bf(acc[s][ct][rr]);
            }

    // ---- phase 2: r = h @ Wr + b ----
#pragma unroll
    for (int s = 0; s < 2; ++s)
#pragma unroll
        for (int ct = 0; ct < NT; ++ct) acc[s][ct] = z;
#pragma unroll
    for (int ct = 0; ct < NT; ++ct)
#pragma unroll
        for (int ks = 0; ks < 4; ++ks) {
            bf16x8 bfv = *(const bf16x8*)(Wrp + ((size_t)(ct * 4 + ks) * 64 + lane) * 8);
            acc[0][ct] = __builtin_amdgcn_mfma_f32_16x16x32_bf16(afrag[0][ks], bfv, acc[0][ct], 0, 0, 0);
            acc[1][ct] = __builtin_amdgcn_mfma_f32_16x16x32_bf16(afrag[1][ks], bfv, acc[1][ct], 0, 0, 0);
        }
#pragma unroll
    for (int s = 0; s < 2; ++s)
#pragma unroll
        for (int ct = 0; ct < NT; ++ct)
#pragma unroll
            for (int rr = 0; rr < 4; ++rr) {
                int row = rowbase + s * 16 + gq * 4 + rr;
                if (row < n)
                    r[(size_t)row * 128 + ct * 16 + c] = f2bf(acc[s][ct][rr] + b[ct * 16 + c]);
            }
}

// ---------------- combine: out = relu?(mean_gather(g) + r) ----------------
// LPNS: log2(lanes per node). GS: g row stride (shorts). r stride fixed 128.
// MODE 0: bf16 out stride 128 (next h).  MODE 1: f32 ne [n,64] + bf16 neb [n,64].
template <int LPNS, bool RELU, int MODE, int GS>
__global__ __launch_bounds__(256) void combine_kernel(
    const short* __restrict__ g, const short* rr,
    const int* __restrict__ off, const int* __restrict__ col,
    short* outb, short* neb, float* nef, int n) {
    int t = blockIdx.x * 256 + threadIdx.x;
    int node = t >> LPNS;
    int q = t & ((1 << LPNS) - 1);
    if (node >= n) return;
    int qo = q * 8;
    int p0 = off[node], p1 = off[node + 1];
    float a[8];
#pragma unroll
    for (int k = 0; k < 8; ++k) a[k] = 0.f;
    int p = p0;
    for (; p + 3 < p1; p += 4) {
        int c0 = col[p], c1 = col[p + 1], c2 = col[p + 2], c3 = col[p + 3];
        bf16x8 u0 = *(const bf16x8*)(g + (size_t)c0 * GS + qo);
        bf16x8 u1 = *(const bf16x8*)(g + (size_t)c1 * GS + qo);
        bf16x8 u2 = *(const bf16x8*)(g + (size_t)c2 * GS + qo);
        bf16x8 u3 = *(const bf16x8*)(g + (size_t)c3 * GS + qo);
#pragma unroll
        for (int k = 0; k < 8; ++k)
            a[k] += (bf2f(u0[k]) + bf2f(u1[k])) + (bf2f(u2[k]) + bf2f(u3[k]));
    }
    for (; p < p1; ++p) {
        bf16x8 u0 = *(const bf16x8*)(g + (size_t)col[p] * GS + qo);
#pragma unroll
        for (int k = 0; k < 8; ++k) a[k] += bf2f(u0[k]);
    }
    int deg = p1 - p0;
    float inv = 1.f / (float)(deg > 1 ? deg : 1);
    bf16x8 rv = *(const bf16x8*)(rr + (size_t)node * 128 + qo);
    float val[8];
#pragma unroll
    for (int k = 0; k < 8; ++k) {
        float v = a[k] * inv + bf2f(rv[k]);
        if (RELU) v = fmaxf(v, 0.f);
        val[k] = v;
    }
    if (MODE == 0) {
        bf16x8 o;
#pragma unroll
        for (int k = 0; k < 8; ++k) o[k] = f2bf(val[k]);
        *(bf16x8*)(outb + (size_t)node * 128 + qo) = o;
    } else {
        float4 f0, f1;
        f0.x = val[0]; f0.y = val[1]; f0.z = val[2]; f0.w = val[3];
        f1.x = val[4]; f1.y = val[5]; f1.z = val[6]; f1.w = val[7];
        *(float4*)(nef + (size_t)node * 64 + qo) = f0;
        *(float4*)(nef + (size_t)node * 64 + qo + 4) = f1;
        bf16x8 o;
#pragma unroll
        for (int k = 0; k < 8; ++k) o[k] = f2bf(val[k]);
        *(bf16x8*)(neb + (size_t)node * 64 + qo) = o;
    }
}

// ---------------- edge MLP: 32 edges/wave, compact neb [NN,64] bf16 ----------------
__global__ __launch_bounds__(256) void edge_mlp_mfma_kernel(
    const short* __restrict__ neb, const int* __restrict__ src, const int* __restrict__ dst,
    const short* __restrict__ Wp, const float* __restrict__ bf1,
    const float* __restrict__ Wf2, const float* __restrict__ bf2,
    float* __restrict__ out, int nE) {
    int wave = (blockIdx.x * 256 + threadIdx.x) >> 6;
    int lane = threadIdx.x & 63;
    int rowbase = wave * 32;
    if (rowbase >= nE) return;
    int g = lane >> 4, c = lane & 15;

    bf16x8 afrag[2][4];
#pragma unroll
    for (int s = 0; s < 2; ++s) {
        int e = rowbase + s * 16 + c;
        const short* rs = neb + (size_t)src[e] * 64;
        const short* rd = neb + (size_t)dst[e] * 64;
        afrag[s][0] = *(const bf16x8*)(rs + g * 8);
        afrag[s][1] = *(const bf16x8*)(rs + 32 + g * 8);
        afrag[s][2] = *(const bf16x8*)(rd + g * 8);
        afrag[s][3] = *(const bf16x8*)(rd + 32 + g * 8);
    }

    f32x4 acc[2][8];
    f32x4 z = {0.f, 0.f, 0.f, 0.f};
#pragma unroll
    for (int s = 0; s < 2; ++s)
#pragma unroll
        for (int ct = 0; ct < 8; ++ct) acc[s][ct] = z;

#pragma unroll
    for (int ct = 0; ct < 8; ++ct)
#pragma unroll
        for (int ks = 0; ks < 4; ++ks) {
            bf16x8 bfv = *(const bf16x8*)(Wp + ((size_t)(ct * 4 + ks) * 64 + lane) * 8);
            acc[0][ct] = __builtin_amdgcn_mfma_f32_16x16x32_bf16(afrag[0][ks], bfv, acc[0][ct], 0, 0, 0);
            acc[1][ct] = __builtin_amdgcn_mfma_f32_16x16x32_bf16(afrag[1][ks], bfv, acc[1][ct], 0, 0, 0);
        }

    float bf1v[8], wf2v[8];
#pragma unroll
    for (int ct = 0; ct < 8; ++ct) {
        bf1v[ct] = bf1[ct * 16 + c];
        wf2v[ct] = Wf2[ct * 16 + c];
    }
    float bias2 = bf2[0];
#pragma unroll
    for (int s = 0; s < 2; ++s)
#pragma unroll
        for (int r = 0; r < 4; ++r) {
            float part = 0.f;
#pragma unroll
            for (int ct = 0; ct < 8; ++ct) {
                float hv = acc[s][ct][r] + bf1v[ct];
                hv = fmaxf(hv, 0.f);
                part = fmaf(hv, wf2v[ct], part);
            }
#pragma unroll
            for (int o = 1; o < 16; o <<= 1)
                part += __shfl_xor(part, o);
            if (c == 0) {
                int row = rowbase + s * 16 + g * 4 + r;
                out[row] = part + bias2;
            }
        }
}

// ---------------- classifier: neb(bf16 compact) @ Wc + bc ----------------
__global__ __launch_bounds__(64, 2) void classifier_kernel(
    const short* __restrict__ neb, const float* __restrict__ Wc,
    const float* __restrict__ bc, float* __restrict__ out, int n) {
    int i = blockIdx.x * 64 + threadIdx.x;
    if (i >= n) return;
    const short* row = neb + (size_t)i * 64;
    bf16x8 r[8];
#pragma unroll
    for (int j = 0; j < 8; ++j) r[j] = *(const bf16x8*)(row + j * 8);
#pragma unroll
    for (int cidx = 0; cidx < 4; ++cidx) {
        float a0 = 0.f, a1 = 0.f, a2 = 0.f, a3 = 0.f;
#pragma unroll
        for (int j = 0; j < 8; ++j) {
            a0 = fmaf(bf2f(r[j][0]), Wc[(j * 8 + 0) * 4 + cidx], a0);
            a1 = fmaf(bf2f(r[j][1]), Wc[(j * 8 + 1) * 4 + cidx], a1);
            a2 = fmaf(bf2f(r[j][2]), Wc[(j * 8 + 2) * 4 + cidx], a2);
            a3 = fmaf(bf2f(r[j][3]), Wc[(j * 8 + 3) * 4 + cidx], a3);
            a0 = fmaf(bf2f(r[j][4]), Wc[(j * 8 + 4) * 4 + cidx], a0);
            a1 = fmaf(bf2f(r[j][5]), Wc[(j * 8 + 5) * 4 + cidx], a1);
            a2 = fmaf(bf2f(r[j][6]), Wc[(j * 8 + 6) * 4 + cidx], a2);
            a3 = fmaf(bf2f(r[j][7]), Wc[(j * 8 + 7) * 4 + cidx], a3);
        }
        out[(size_t)i * 4 + cidx] = bc[cidx] + (a0 + a1) + (a2 + a3);
    }
}

extern "C" void kernel_launch(void* const* d_in, const int* in_sizes, int n_in,
                              void* d_out, int out_size, void* d_ws, size_t ws_size,
                              hipStream_t stream) {
    const float* x   = (const float*)d_in[0];
    const int*   ei  = (const int*)d_in[1];
    const int*   src = ei;
    const int*   dst = ei + NE;
    const float* Wl0 = (const float*)d_in[2];
    const float* Wr0 = (const float*)d_in[3];
    const float* b0  = (const float*)d_in[4];
    const float* Wl1 = (const float*)d_in[5];
    const float* Wr1 = (const float*)d_in[6];
    const float* b1  = (const float*)d_in[7];
    const float* Wl2 = (const float*)d_in[8];
    const float* Wr2 = (const float*)d_in[9];
    const float* b2  = (const float*)d_in[10];
    const float* Wf1 = (const float*)d_in[11];
    const float* bf1 = (const float*)d_in[12];
    const float* Wf2 = (const float*)d_in[13];
    const float* bf2 = (const float*)d_in[14];
    const float* Wc  = (const float*)d_in[15];
    const float* bc  = (const float*)d_in[16];

    // ---- workspace carve-up (~35.8 MB; <= 36 MiB proven available) ----
    short* sp = (short*)d_ws;
    short* W0lp = sp; sp += 128 * 128;
    short* W0rp = sp; sp += 128 * 128;
    short* W1lp = sp; sp += 128 * 128;
    short* W1rp = sp; sp += 128 * 128;
    short* W2lp = sp; sp += 128 * 64;
    short* W2rp = sp; sp += 128 * 64;
    short* Wfp  = sp; sp += 128 * 128;
    short* gb   = sp; sp += (size_t)NN * 128;   // g rows (layer2 uses first NN*64)
    short* hb   = sp; sp += (size_t)NN * 128;   // xb -> h (r written in place)
    short* neb  = sp; sp += (size_t)NN * 64;    // compact bf16 node embeddings
    int* ip = (int*)sp;
    int* off    = ip; ip += 50008;
    int* cursor = ip; ip += 50000;               // also deg
    int* col    = ip; ip += 800000;
    int* bsum   = ip; ip += 256;

    float* ne = (float*)d_out;               // [NN,64]
    float* cf = ne + (size_t)NN * 64;        // [NE]
    float* sc = cf + NE;                     // [NN,4]

    int* deg = cursor;
    const int NB = (NN + 255) / 256;

    // --- CSR build ---
    hipMemsetAsync(deg, 0, NN * sizeof(int), stream);
    count_deg_kernel<<<(NE + 255) / 256, 256, 0, stream>>>(dst, deg, NE);
    scan1_kernel<<<NB, 256, 0, stream>>>(deg, off, bsum, NN);
    scan2_kernel<<<1, 256, 0, stream>>>(bsum, NB);
    scan3_kernel<<<NB, 256, 0, stream>>>(off, bsum, cursor, NN, NE);
    fill_kernel<<<(NE + 255) / 256, 256, 0, stream>>>(src, dst, cursor, col, NE);

    // --- x -> bf16 (into hb region), merged weight packs ---
    cvt_bf16_kernel<<<(NN * 16 + 255) / 256, 256, 0, stream>>>(x, hb, NN * 16);
    pack_all_kernel<<<48, 256, 0, stream>>>(Wl0, Wr0, Wl1, Wr1, Wl2, Wr2, Wf1,
                                            W0lp, W0rp, W1lp, W1rp, W2lp, W2rp, Wfp);

    int sgrid  = ((NN + 31) / 32 + 3) / 4;       // 391
    int cgrid1 = (NN * 16 + 255) / 256;          // 3125
    int cgrid2 = (NN * 8 + 255) / 256;           // 1563
    int egrid  = (NE / 32) / 4;                  // 6250

    // --- layer 0: g0=xb@Wl0 -> gb ; r0=xb@Wr0+b0 -> hb (in place); combine -> hb ---
    gemm_tf_kernel<8><<<sgrid, 256, 0, stream>>>(hb, W0lp, W0rp, b0, gb, hb, NN);
    combine_kernel<4, true, 0, 128><<<cgrid1, 256, 0, stream>>>(gb, hb, off, col, hb, nullptr, nullptr, NN);
    // --- layer 1 ---
    gemm_tf_kernel<8><<<sgrid, 256, 0, stream>>>(hb, W1lp, W1rp, b1, gb, hb, NN);
    combine_kernel<4, true, 0, 128><<<cgrid1, 256, 0, stream>>>(gb, hb, off, col, hb, nullptr, nullptr, NN);
    // --- layer 2: g2 64-wide -> gb ; r2 -> hb (stride 128); combine -> ne + neb ---
    gemm_tf_kernel<4><<<sgrid, 256, 0, stream>>>(hb, W2lp, W2rp, b2, gb, hb, NN);
    combine_kernel<3, false, 1, 64><<<cgrid2, 256, 0, stream>>>(gb, hb, off, col, nullptr, neb, ne, NN);

    // --- heads ---
    edge_mlp_mfma_kernel<<<egrid, 256, 0, stream>>>(neb, src, dst, Wfp, bf1, Wf2, bf2, cf, NE);
    classifier_kernel<<<(NN + 63) / 64, 64, 0, stream>>>(neb, Wc, bc, sc, NN);
}

// Round 8
// 308.533 us; speedup vs baseline: 1.1642x; 1.0479x over previous
//
#include <hip/hip_runtime.h>

#define NN 50000
#define NE 800000

typedef __attribute__((ext_vector_type(8))) short bf16x8;
typedef __attribute__((ext_vector_type(4))) float f32x4;
typedef __attribute__((ext_vector_type(2))) float f32x2;

__device__ inline short f2bf(float f) {
    union { float f; unsigned u; } v; v.f = f;
    unsigned r = v.u + 0x7fffu + ((v.u >> 16) & 1u);
    return (short)(r >> 16);
}
__device__ inline float bf2f(short s) {
    union { unsigned u; float f; } v;
    v.u = ((unsigned)(unsigned short)s) << 16;
    return v.f;
}

// ---------------- CSR build ----------------
__global__ __launch_bounds__(256) void count_deg_kernel(const int* __restrict__ dst,
                                                        int* __restrict__ deg, int n) {
    int e = blockIdx.x * 256 + threadIdx.x;
    if (e < n) atomicAdd(&deg[dst[e]], 1);
}

__global__ __launch_bounds__(256) void scan1_kernel(const int* __restrict__ deg,
                                                    int* __restrict__ off,
                                                    int* __restrict__ bsum, int n) {
    __shared__ int s[256];
    int t = threadIdx.x;
    int i = blockIdx.x * 256 + t;
    int v = (i < n) ? deg[i] : 0;
    s[t] = v;
    __syncthreads();
    for (int d = 1; d < 256; d <<= 1) {
        int u = (t >= d) ? s[t - d] : 0;
        __syncthreads();
        s[t] += u;
        __syncthreads();
    }
    if (i < n) off[i] = s[t] - v;
    if (t == 255) bsum[blockIdx.x] = s[255];
}

__global__ __launch_bounds__(256) void scan2_kernel(int* __restrict__ bsum, int nb) {
    __shared__ int s[256];
    int t = threadIdx.x;
    int v = (t < nb) ? bsum[t] : 0;
    s[t] = v;
    __syncthreads();
    for (int d = 1; d < 256; d <<= 1) {
        int u = (t >= d) ? s[t - d] : 0;
        __syncthreads();
        s[t] += u;
        __syncthreads();
    }
    if (t < nb) bsum[t] = s[t] - v;
}

__global__ __launch_bounds__(256) void scan3_kernel(int* __restrict__ off,
                                                    const int* __restrict__ bsum,
                                                    int* __restrict__ cursor, int n, int total) {
    int i = blockIdx.x * 256 + threadIdx.x;
    if (i < n) {
        int v = off[i] + bsum[i >> 8];
        off[i] = v;
        cursor[i] = v;
    }
    if (i == 0) off[n] = total;
}

__global__ __launch_bounds__(256) void fill_kernel(const int* __restrict__ src,
                                                   const int* __restrict__ dst,
                                                   int* __restrict__ cursor,
                                                   int* __restrict__ col, int n) {
    int e = blockIdx.x * 256 + threadIdx.x;
    if (e < n) {
        int p = atomicAdd(&cursor[dst[e]], 1);
        col[p] = src[e];
    }
}

// ---------------- pack one f32 KxN matrix into bf16 MFMA B-fragments --------------
__device__ inline void pack_one(const float* B, int K, int N, short* out, int t) {
    int l = t & 63;
    int fs = t >> 6;
    int KS = K >> 5;
    int ct = fs / KS, ks = fs - ct * KS;
    int coln = ct * 16 + (l & 15);
    int k0 = ks * 32 + (l >> 4) * 8;
    bf16x8 v;
#pragma unroll
    for (int j = 0; j < 8; ++j)
        v[j] = f2bf(B[(size_t)(k0 + j) * N + coln]);
    *(bf16x8*)(out + (size_t)t * 8) = v;
}

__global__ __launch_bounds__(256) void pack_all_kernel(
    const float* __restrict__ Wl0, const float* __restrict__ Wr0,
    const float* __restrict__ Wl1, const float* __restrict__ Wr1,
    const float* __restrict__ Wl2, const float* __restrict__ Wr2,
    const float* __restrict__ Wf1,
    short* W0lp, short* W0rp, short* W1lp, short* W1rp,
    short* W2lp, short* W2rp, short* Wfp) {
    int t = blockIdx.x * 256 + threadIdx.x;
    if (t < 2048)              pack_one(Wl0, 128, 128, W0lp, t);
    else if (t < 4096)         pack_one(Wr0, 128, 128, W0rp, t - 2048);
    else if (t < 6144)         pack_one(Wl1, 128, 128, W1lp, t - 4096);
    else if (t < 8192)         pack_one(Wr1, 128, 128, W1rp, t - 6144);
    else if (t < 9216)         pack_one(Wl2, 128, 64,  W2lp, t - 8192);
    else if (t < 10240)        pack_one(Wr2, 128, 64,  W2rp, t - 9216);
    else if (t < 12288)        pack_one(Wf1, 128, 128, Wfp,  t - 10240);
}

// ---------------- transform GEMM: g = h@Wl ; r = h@Wr + b  (K=128) ----------------
// SRC_F32: A rows read from f32 (layer 0 reads x directly).
// G_FP8: g stored as fp8 e4m3 bytes, row stride NT*16 bytes; else bf16 shorts.
// r always bf16, stride 128 shorts, written IN-PLACE over the h buffer (afrag
// for both phases is loaded into regs before any store; rows are wave-private).
template <int NT, bool SRC_F32, bool G_FP8>
__global__ __launch_bounds__(256) void gemm_tf_kernel(
    const void* hsrc, const short* __restrict__ Wlp, const short* __restrict__ Wrp,
    const float* __restrict__ b, void* g, short* r, int n) {
    int wave = (blockIdx.x * 256 + threadIdx.x) >> 6;
    int lane = threadIdx.x & 63;
    int rowbase = wave * 32;
    if (rowbase >= n) return;
    int gq = lane >> 4, c = lane & 15;

    bf16x8 afrag[2][4];
#pragma unroll
    for (int s = 0; s < 2; ++s) {
        int i = rowbase + s * 16 + c;
        if (i >= n) i = n - 1;
        if (SRC_F32) {
            const float* xr = (const float*)hsrc + (size_t)i * 128;
#pragma unroll
            for (int ks = 0; ks < 4; ++ks) {
                const float* p = xr + ks * 32 + gq * 8;
                float4 v0 = *(const float4*)p;
                float4 v1 = *(const float4*)(p + 4);
                bf16x8 a;
                a[0] = f2bf(v0.x); a[1] = f2bf(v0.y); a[2] = f2bf(v0.z); a[3] = f2bf(v0.w);
                a[4] = f2bf(v1.x); a[5] = f2bf(v1.y); a[6] = f2bf(v1.z); a[7] = f2bf(v1.w);
                afrag[s][ks] = a;
            }
        } else {
            const short* hr = (const short*)hsrc + (size_t)i * 128;
#pragma unroll
            for (int ks = 0; ks < 4; ++ks)
                afrag[s][ks] = *(const bf16x8*)(hr + ks * 32 + gq * 8);
        }
    }

    f32x4 acc[2][NT];
    f32x4 z = {0.f, 0.f, 0.f, 0.f};
    const int NG = NT * 16;

    // ---- phase 1: g = h @ Wl ----
#pragma unroll
    for (int s = 0; s < 2; ++s)
#pragma unroll
        for (int ct = 0; ct < NT; ++ct) acc[s][ct] = z;
#pragma unroll
    for (int ct = 0; ct < NT; ++ct)
#pragma unroll
        for (int ks = 0; ks < 4; ++ks) {
            bf16x8 bfv = *(const bf16x8*)(Wlp + ((size_t)(ct * 4 + ks) * 64 + lane) * 8);
            acc[0][ct] = __builtin_amdgcn_mfma_f32_16x16x32_bf16(afrag[0][ks], bfv, acc[0][ct], 0, 0, 0);
            acc[1][ct] = __builtin_amdgcn_mfma_f32_16x16x32_bf16(afrag[1][ks], bfv, acc[1][ct], 0, 0, 0);
        }
#pragma unroll
    for (int s = 0; s < 2; ++s)
#pragma unroll
        for (int ct = 0; ct < NT; ++ct)
#pragma unroll
            for (int rr = 0; rr < 4; ++rr) {
                int row = rowbase + s * 16 + gq * 4 + rr;
                if (row < n) {
                    float v = acc[s][ct][rr];
                    if (G_FP8) {
                        unsigned pk = __builtin_amdgcn_cvt_pk_fp8_f32(v, v, 0u, false);
                        ((unsigned char*)g)[(size_t)row * NG + ct * 16 + c] = (unsigned char)pk;
                    } else {
                        ((short*)g)[(size_t)row * NG + ct * 16 + c] = f2bf(v);
                    }
                }
            }

    // ---- phase 2: r = h @ Wr + b ----
#pragma unroll
    for (int s = 0; s < 2; ++s)
#pragma unroll
        for (int ct = 0; ct < NT; ++ct) acc[s][ct] = z;
#pragma unroll
    for (int ct = 0; ct < NT; ++ct)
#pragma unroll
        for (int ks = 0; ks < 4; ++ks) {
            bf16x8 bfv = *(const bf16x8*)(Wrp + ((size_t)(ct * 4 + ks) * 64 + lane) * 8);
            acc[0][ct] = __builtin_amdgcn_mfma_f32_16x16x32_bf16(afrag[0][ks], bfv, acc[0][ct], 0, 0, 0);
            acc[1][ct] = __builtin_amdgcn_mfma_f32_16x16x32_bf16(afrag[1][ks], bfv, acc[1][ct], 0, 0, 0);
        }
#pragma unroll
    for (int s = 0; s < 2; ++s)
#pragma unroll
        for (int ct = 0; ct < NT; ++ct)
#pragma unroll
            for (int rr = 0; rr < 4; ++rr) {
                int row = rowbase + s * 16 + gq * 4 + rr;
                if (row < n)
                    r[(size_t)row * 128 + ct * 16 + c] = f2bf(acc[s][ct][rr] + b[ct * 16 + c]);
            }
}

// ---------------- combine (fp8 g): h' = relu(mean_gather(g8) + r) ----------------
// g8 rows: 128 fp8 bytes. 16 lanes/node, 8 cols/lane. r/out bf16 stride 128 (in place).
__global__ __launch_bounds__(256) void combine_fp8_kernel(
    const unsigned char* __restrict__ g8, const short* rr,
    const int* __restrict__ off, const int* __restrict__ col,
    short* outb, int n) {
    int t = blockIdx.x * 256 + threadIdx.x;
    int node = t >> 4, q = t & 15;
    if (node >= n) return;
    int qo = q * 8;
    int p0 = off[node], p1 = off[node + 1];
    float a[8];
#pragma unroll
    for (int k = 0; k < 8; ++k) a[k] = 0.f;
    int p = p0;
    for (; p + 3 < p1; p += 4) {
        uint2 u0 = *(const uint2*)(g8 + (size_t)col[p] * 128 + qo);
        uint2 u1 = *(const uint2*)(g8 + (size_t)col[p + 1] * 128 + qo);
        uint2 u2 = *(const uint2*)(g8 + (size_t)col[p + 2] * 128 + qo);
        uint2 u3 = *(const uint2*)(g8 + (size_t)col[p + 3] * 128 + qo);
#pragma unroll
        for (int w = 0; w < 4; ++w) {
            uint2 u = (w == 0) ? u0 : (w == 1) ? u1 : (w == 2) ? u2 : u3;
            f32x2 d0 = __builtin_amdgcn_cvt_pk_f32_fp8((int)u.x, false);
            f32x2 d1 = __builtin_amdgcn_cvt_pk_f32_fp8((int)u.x, true);
            f32x2 d2 = __builtin_amdgcn_cvt_pk_f32_fp8((int)u.y, false);
            f32x2 d3 = __builtin_amdgcn_cvt_pk_f32_fp8((int)u.y, true);
            a[0] += d0.x; a[1] += d0.y; a[2] += d1.x; a[3] += d1.y;
            a[4] += d2.x; a[5] += d2.y; a[6] += d3.x; a[7] += d3.y;
        }
    }
    for (; p < p1; ++p) {
        uint2 u = *(const uint2*)(g8 + (size_t)col[p] * 128 + qo);
        f32x2 d0 = __builtin_amdgcn_cvt_pk_f32_fp8((int)u.x, false);
        f32x2 d1 = __builtin_amdgcn_cvt_pk_f32_fp8((int)u.x, true);
        f32x2 d2 = __builtin_amdgcn_cvt_pk_f32_fp8((int)u.y, false);
        f32x2 d3 = __builtin_amdgcn_cvt_pk_f32_fp8((int)u.y, true);
        a[0] += d0.x; a[1] += d0.y; a[2] += d1.x; a[3] += d1.y;
        a[4] += d2.x; a[5] += d2.y; a[6] += d3.x; a[7] += d3.y;
    }
    int deg = p1 - p0;
    float inv = 1.f / (float)(deg > 1 ? deg : 1);
    bf16x8 rv = *(const bf16x8*)(rr + (size_t)node * 128 + qo);
    bf16x8 o;
#pragma unroll
    for (int k = 0; k < 8; ++k) {
        float v = a[k] * inv + bf2f(rv[k]);
        o[k] = f2bf(fmaxf(v, 0.f));
    }
    *(bf16x8*)(outb + (size_t)node * 128 + qo) = o;
}

// ---------------- combine (bf16 g, layer 2): ne = mean_gather(g) + r ----------------
// g rows: 64 bf16 (stride 64). 8 lanes/node. Writes f32 ne (d_out) + bf16 neb.
__global__ __launch_bounds__(256) void combine_l2_kernel(
    const short* __restrict__ g, const short* rr,
    const int* __restrict__ off, const int* __restrict__ col,
    short* neb, float* nef, int n) {
    int t = blockIdx.x * 256 + threadIdx.x;
    int node = t >> 3, q = t & 7;
    if (node >= n) return;
    int qo = q * 8;
    int p0 = off[node], p1 = off[node + 1];
    float a[8];
#pragma unroll
    for (int k = 0; k < 8; ++k) a[k] = 0.f;
    int p = p0;
    for (; p + 3 < p1; p += 4) {
        bf16x8 u0 = *(const bf16x8*)(g + (size_t)col[p] * 64 + qo);
        bf16x8 u1 = *(const bf16x8*)(g + (size_t)col[p + 1] * 64 + qo);
        bf16x8 u2 = *(const bf16x8*)(g + (size_t)col[p + 2] * 64 + qo);
        bf16x8 u3 = *(const bf16x8*)(g + (size_t)col[p + 3] * 64 + qo);
#pragma unroll
        for (int k = 0; k < 8; ++k)
            a[k] += (bf2f(u0[k]) + bf2f(u1[k])) + (bf2f(u2[k]) + bf2f(u3[k]));
    }
    for (; p < p1; ++p) {
        bf16x8 u0 = *(const bf16x8*)(g + (size_t)col[p] * 64 + qo);
#pragma unroll
        for (int k = 0; k < 8; ++k) a[k] += bf2f(u0[k]);
    }
    int deg = p1 - p0;
    float inv = 1.f / (float)(deg > 1 ? deg : 1);
    bf16x8 rv = *(const bf16x8*)(rr + (size_t)node * 128 + qo);
    float val[8];
#pragma unroll
    for (int k = 0; k < 8; ++k) val[k] = a[k] * inv + bf2f(rv[k]);
    float4 f0, f1;
    f0.x = val[0]; f0.y = val[1]; f0.z = val[2]; f0.w = val[3];
    f1.x = val[4]; f1.y = val[5]; f1.z = val[6]; f1.w = val[7];
    *(float4*)(nef + (size_t)node * 64 + qo) = f0;
    *(float4*)(nef + (size_t)node * 64 + qo + 4) = f1;
    bf16x8 o;
#pragma unroll
    for (int k = 0; k < 8; ++k) o[k] = f2bf(val[k]);
    *(bf16x8*)(neb + (size_t)node * 64 + qo) = o;
}

// ---------------- edge MLP: 32 edges/wave, compact neb [NN,64] bf16 ----------------
__global__ __launch_bounds__(256) void edge_mlp_mfma_kernel(
    const short* __restrict__ neb, const int* __restrict__ src, const int* __restrict__ dst,
    const short* __restrict__ Wp, const float* __restrict__ bf1,
    const float* __restrict__ Wf2, const float* __restrict__ bf2,
    float* __restrict__ out, int nE) {
    int wave = (blockIdx.x * 256 + threadIdx.x) >> 6;
    int lane = threadIdx.x & 63;
    int rowbase = wave * 32;
    if (rowbase >= nE) return;
    int g = lane >> 4, c = lane & 15;

    bf16x8 afrag[2][4];
#pragma unroll
    for (int s = 0; s < 2; ++s) {
        int e = rowbase + s * 16 + c;
        const short* rs = neb + (size_t)src[e] * 64;
        const short* rd = neb + (size_t)dst[e] * 64;
        afrag[s][0] = *(const bf16x8*)(rs + g * 8);
        afrag[s][1] = *(const bf16x8*)(rs + 32 + g * 8);
        afrag[s][2] = *(const bf16x8*)(rd + g * 8);
        afrag[s][3] = *(const bf16x8*)(rd + 32 + g * 8);
    }

    f32x4 acc[2][8];
    f32x4 z = {0.f, 0.f, 0.f, 0.f};
#pragma unroll
    for (int s = 0; s < 2; ++s)
#pragma unroll
        for (int ct = 0; ct < 8; ++ct) acc[s][ct] = z;

#pragma unroll
    for (int ct = 0; ct < 8; ++ct)
#pragma unroll
        for (int ks = 0; ks < 4; ++ks) {
            bf16x8 bfv = *(const bf16x8*)(Wp + ((size_t)(ct * 4 + ks) * 64 + lane) * 8);
            acc[0][ct] = __builtin_amdgcn_mfma_f32_16x16x32_bf16(afrag[0][ks], bfv, acc[0][ct], 0, 0, 0);
            acc[1][ct] = __builtin_amdgcn_mfma_f32_16x16x32_bf16(afrag[1][ks], bfv, acc[1][ct], 0, 0, 0);
        }

    float bf1v[8], wf2v[8];
#pragma unroll
    for (int ct = 0; ct < 8; ++ct) {
        bf1v[ct] = bf1[ct * 16 + c];
        wf2v[ct] = Wf2[ct * 16 + c];
    }
    float bias2 = bf2[0];
#pragma unroll
    for (int s = 0; s < 2; ++s)
#pragma unroll
        for (int r = 0; r < 4; ++r) {
            float part = 0.f;
#pragma unroll
            for (int ct = 0; ct < 8; ++ct) {
                float hv = acc[s][ct][r] + bf1v[ct];
                hv = fmaxf(hv, 0.f);
                part = fmaf(hv, wf2v[ct], part);
            }
#pragma unroll
            for (int o = 1; o < 16; o <<= 1)
                part += __shfl_xor(part, o);
            if (c == 0) {
                int row = rowbase + s * 16 + g * 4 + r;
                out[row] = part + bias2;
            }
        }
}

// ---------------- classifier: neb(bf16 compact) @ Wc + bc ----------------
__global__ __launch_bounds__(64, 2) void classifier_kernel(
    const short* __restrict__ neb, const float* __restrict__ Wc,
    const float* __restrict__ bc, float* __restrict__ out, int n) {
    int i = blockIdx.x * 64 + threadIdx.x;
    if (i >= n) return;
    const short* row = neb + (size_t)i * 64;
    bf16x8 r[8];
#pragma unroll
    for (int j = 0; j < 8; ++j) r[j] = *(const bf16x8*)(row + j * 8);
#pragma unroll
    for (int cidx = 0; cidx < 4; ++cidx) {
        float a0 = 0.f, a1 = 0.f, a2 = 0.f, a3 = 0.f;
#pragma unroll
        for (int j = 0; j < 8; ++j) {
            a0 = fmaf(bf2f(r[j][0]), Wc[(j * 8 + 0) * 4 + cidx], a0);
            a1 = fmaf(bf2f(r[j][1]), Wc[(j * 8 + 1) * 4 + cidx], a1);
            a2 = fmaf(bf2f(r[j][2]), Wc[(j * 8 + 2) * 4 + cidx], a2);
            a3 = fmaf(bf2f(r[j][3]), Wc[(j * 8 + 3) * 4 + cidx], a3);
            a0 = fmaf(bf2f(r[j][4]), Wc[(j * 8 + 4) * 4 + cidx], a0);
            a1 = fmaf(bf2f(r[j][5]), Wc[(j * 8 + 5) * 4 + cidx], a1);
            a2 = fmaf(bf2f(r[j][6]), Wc[(j * 8 + 6) * 4 + cidx], a2);
            a3 = fmaf(bf2f(r[j][7]), Wc[(j * 8 + 7) * 4 + cidx], a3);
        }
        out[(size_t)i * 4 + cidx] = bc[cidx] + (a0 + a1) + (a2 + a3);
    }
}

extern "C" void kernel_launch(void* const* d_in, const int* in_sizes, int n_in,
                              void* d_out, int out_size, void* d_ws, size_t ws_size,
                              hipStream_t stream) {
    const float* x   = (const float*)d_in[0];
    const int*   ei  = (const int*)d_in[1];
    const int*   src = ei;
    const int*   dst = ei + NE;
    const float* Wl0 = (const float*)d_in[2];
    const float* Wr0 = (const float*)d_in[3];
    const float* b0  = (const float*)d_in[4];
    const float* Wl1 = (const float*)d_in[5];
    const float* Wr1 = (const float*)d_in[6];
    const float* b1  = (const float*)d_in[7];
    const float* Wl2 = (const float*)d_in[8];
    const float* Wr2 = (const float*)d_in[9];
    const float* b2  = (const float*)d_in[10];
    const float* Wf1 = (const float*)d_in[11];
    const float* bf1 = (const float*)d_in[12];
    const float* Wf2 = (const float*)d_in[13];
    const float* bf2 = (const float*)d_in[14];
    const float* Wc  = (const float*)d_in[15];
    const float* bc  = (const float*)d_in[16];

    // ---- workspace carve-up (~29.4 MB; well under proven-safe 36 MiB) ----
    short* sp = (short*)d_ws;
    short* W0lp = sp; sp += 128 * 128;
    short* W0rp = sp; sp += 128 * 128;
    short* W1lp = sp; sp += 128 * 128;
    short* W1rp = sp; sp += 128 * 128;
    short* W2lp = sp; sp += 128 * 64;
    short* W2rp = sp; sp += 128 * 64;
    short* Wfp  = sp; sp += 128 * 128;
    short* gb   = sp; sp += (size_t)NN * 64;    // 6.4 MB: fp8 g [NN,128] bytes OR bf16 g2 [NN,64]
    short* hb   = sp; sp += (size_t)NN * 128;   // 12.8 MB: r/h rows (in place)
    short* neb  = sp; sp += (size_t)NN * 64;    // 6.4 MB: compact bf16 node embeddings
    int* ip = (int*)sp;
    int* off    = ip; ip += 50008;
    int* cursor = ip; ip += 50000;               // also deg
    int* col    = ip; ip += 800000;
    int* bsum   = ip; ip += 256;

    float* ne = (float*)d_out;               // [NN,64]
    float* cf = ne + (size_t)NN * 64;        // [NE]
    float* sc = cf + NE;                     // [NN,4]

    int* deg = cursor;
    const int NB = (NN + 255) / 256;

    // --- CSR build ---
    hipMemsetAsync(deg, 0, NN * sizeof(int), stream);
    count_deg_kernel<<<(NE + 255) / 256, 256, 0, stream>>>(dst, deg, NE);
    scan1_kernel<<<NB, 256, 0, stream>>>(deg, off, bsum, NN);
    scan2_kernel<<<1, 256, 0, stream>>>(bsum, NB);
    scan3_kernel<<<NB, 256, 0, stream>>>(off, bsum, cursor, NN, NE);
    fill_kernel<<<(NE + 255) / 256, 256, 0, stream>>>(src, dst, cursor, col, NE);

    // --- weight packs ---
    pack_all_kernel<<<48, 256, 0, stream>>>(Wl0, Wr0, Wl1, Wr1, Wl2, Wr2, Wf1,
                                            W0lp, W0rp, W1lp, W1rp, W2lp, W2rp, Wfp);

    int sgrid  = ((NN + 31) / 32 + 3) / 4;       // 391
    int cgrid1 = (NN * 16 + 255) / 256;          // 3125
    int cgrid2 = (NN * 8 + 255) / 256;           // 1563
    int egrid  = (NE / 32) / 4;                  // 6250

    // --- layer 0: A from f32 x; g0 fp8 -> gb; r0 -> hb; combine -> hb ---
    gemm_tf_kernel<8, true, true><<<sgrid, 256, 0, stream>>>(x, W0lp, W0rp, b0, gb, hb, NN);
    combine_fp8_kernel<<<cgrid1, 256, 0, stream>>>((const unsigned char*)gb, hb, off, col, hb, NN);
    // --- layer 1 ---
    gemm_tf_kernel<8, false, true><<<sgrid, 256, 0, stream>>>(hb, W1lp, W1rp, b1, gb, hb, NN);
    combine_fp8_kernel<<<cgrid1, 256, 0, stream>>>((const unsigned char*)gb, hb, off, col, hb, NN);
    // --- layer 2: g2 bf16 64-wide -> gb; r2 -> hb; combine -> ne + neb ---
    gemm_tf_kernel<4, false, false><<<sgrid, 256, 0, stream>>>(hb, W2lp, W2rp, b2, gb, hb, NN);
    combine_l2_kernel<<<cgrid2, 256, 0, stream>>>(gb, hb, off, col, neb, ne, NN);

    // --- heads ---
    edge_mlp_mfma_kernel<<<egrid, 256, 0, stream>>>(neb, src, dst, Wfp, bf1, Wf2, bf2, cf, NE);
    classifier_kernel<<<(NN + 63) / 64, 64, 0, stream>>>(neb, Wc, bc, sc, NN);
}

// Round 9
// 303.391 us; speedup vs baseline: 1.1839x; 1.0169x over previous
//
#include <hip/hip_runtime.h>

#define NN 50000
#define NE 800000

typedef __attribute__((ext_vector_type(8))) short bf16x8;
typedef __attribute__((ext_vector_type(4))) float f32x4;
typedef __attribute__((ext_vector_type(2))) float f32x2;

__device__ inline short f2bf(float f) {
    union { float f; unsigned u; } v; v.f = f;
    unsigned r = v.u + 0x7fffu + ((v.u >> 16) & 1u);
    return (short)(r >> 16);
}
__device__ inline float bf2f(short s) {
    union { unsigned u; float f; } v;
    v.u = ((unsigned)(unsigned short)s) << 16;
    return v.f;
}

// ---------------- CSR build ----------------
__global__ __launch_bounds__(256) void count_deg_kernel(const int* __restrict__ dst,
                                                        int* __restrict__ deg, int n) {
    int e = blockIdx.x * 256 + threadIdx.x;
    if (e < n) atomicAdd(&deg[dst[e]], 1);
}

__global__ __launch_bounds__(256) void scan1_kernel(const int* __restrict__ deg,
                                                    int* __restrict__ off,
                                                    int* __restrict__ bsum, int n) {
    __shared__ int s[256];
    int t = threadIdx.x;
    int i = blockIdx.x * 256 + t;
    int v = (i < n) ? deg[i] : 0;
    s[t] = v;
    __syncthreads();
    for (int d = 1; d < 256; d <<= 1) {
        int u = (t >= d) ? s[t - d] : 0;
        __syncthreads();
        s[t] += u;
        __syncthreads();
    }
    if (i < n) off[i] = s[t] - v;
    if (t == 255) bsum[blockIdx.x] = s[255];
}

__global__ __launch_bounds__(256) void scan2_kernel(int* __restrict__ bsum, int nb) {
    __shared__ int s[256];
    int t = threadIdx.x;
    int v = (t < nb) ? bsum[t] : 0;
    s[t] = v;
    __syncthreads();
    for (int d = 1; d < 256; d <<= 1) {
        int u = (t >= d) ? s[t - d] : 0;
        __syncthreads();
        s[t] += u;
        __syncthreads();
    }
    if (t < nb) bsum[t] = s[t] - v;
}

__global__ __launch_bounds__(256) void scan3_kernel(int* __restrict__ off,
                                                    const int* __restrict__ bsum,
                                                    int* __restrict__ cursor, int n, int total) {
    int i = blockIdx.x * 256 + threadIdx.x;
    if (i < n) {
        int v = off[i] + bsum[i >> 8];
        off[i] = v;
        cursor[i] = v;
    }
    if (i == 0) off[n] = total;
}

// fill CSR; optionally record pos[e] = CSR position of edge e (coalesced by e)
__global__ __launch_bounds__(256) void fill_kernel(const int* __restrict__ src,
                                                   const int* __restrict__ dst,
                                                   int* __restrict__ cursor,
                                                   int* __restrict__ col,
                                                   int* __restrict__ pos, int n) {
    int e = blockIdx.x * 256 + threadIdx.x;
    if (e < n) {
        int p = atomicAdd(&cursor[dst[e]], 1);
        col[p] = src[e];
        if (pos) pos[e] = p;
    }
}

// per-position dst node id (ushort) from CSR ranges
__global__ __launch_bounds__(256) void edst_fill_kernel(const int* __restrict__ off,
                                                        unsigned short* __restrict__ edst, int n) {
    int i = blockIdx.x * 256 + threadIdx.x;
    if (i < n) {
        int p0 = off[i], p1 = off[i + 1];
        for (int p = p0; p < p1; ++p) edst[p] = (unsigned short)i;
    }
}

// ---------------- pack one f32 KxN matrix into bf16 MFMA B-fragments --------------
__device__ inline void pack_one(const float* B, int K, int N, short* out, int t) {
    int l = t & 63;
    int fs = t >> 6;
    int KS = K >> 5;
    int ct = fs / KS, ks = fs - ct * KS;
    int coln = ct * 16 + (l & 15);
    int k0 = ks * 32 + (l >> 4) * 8;
    bf16x8 v;
#pragma unroll
    for (int j = 0; j < 8; ++j)
        v[j] = f2bf(B[(size_t)(k0 + j) * N + coln]);
    *(bf16x8*)(out + (size_t)t * 8) = v;
}

__global__ __launch_bounds__(256) void pack_all_kernel(
    const float* __restrict__ Wl0, const float* __restrict__ Wr0,
    const float* __restrict__ Wl1, const float* __restrict__ Wr1,
    const float* __restrict__ Wl2, const float* __restrict__ Wr2,
    const float* __restrict__ Wf1,
    short* W0lp, short* W0rp, short* W1lp, short* W1rp,
    short* W2lp, short* W2rp, short* Wfp) {
    int t = blockIdx.x * 256 + threadIdx.x;
    if (t < 2048)              pack_one(Wl0, 128, 128, W0lp, t);
    else if (t < 4096)         pack_one(Wr0, 128, 128, W0rp, t - 2048);
    else if (t < 6144)         pack_one(Wl1, 128, 128, W1lp, t - 4096);
    else if (t < 8192)         pack_one(Wr1, 128, 128, W1rp, t - 6144);
    else if (t < 9216)         pack_one(Wl2, 128, 64,  W2lp, t - 8192);
    else if (t < 10240)        pack_one(Wr2, 128, 64,  W2rp, t - 9216);
    else if (t < 12288)        pack_one(Wf1, 128, 128, Wfp,  t - 10240);
}

// ---------------- transform GEMM: g = h@Wl ; r = h@Wr + b  (K=128) ----------------
template <int NT, bool SRC_F32, bool G_FP8>
__global__ __launch_bounds__(256) void gemm_tf_kernel(
    const void* hsrc, const short* __restrict__ Wlp, const short* __restrict__ Wrp,
    const float* __restrict__ b, void* g, short* r, int n) {
    int wave = (blockIdx.x * 256 + threadIdx.x) >> 6;
    int lane = threadIdx.x & 63;
    int rowbase = wave * 32;
    if (rowbase >= n) return;
    int gq = lane >> 4, c = lane & 15;

    bf16x8 afrag[2][4];
#pragma unroll
    for (int s = 0; s < 2; ++s) {
        int i = rowbase + s * 16 + c;
        if (i >= n) i = n - 1;
        if (SRC_F32) {
            const float* xr = (const float*)hsrc + (size_t)i * 128;
#pragma unroll
            for (int ks = 0; ks < 4; ++ks) {
                const float* p = xr + ks * 32 + gq * 8;
                float4 v0 = *(const float4*)p;
                float4 v1 = *(const float4*)(p + 4);
                bf16x8 a;
                a[0] = f2bf(v0.x); a[1] = f2bf(v0.y); a[2] = f2bf(v0.z); a[3] = f2bf(v0.w);
                a[4] = f2bf(v1.x); a[5] = f2bf(v1.y); a[6] = f2bf(v1.z); a[7] = f2bf(v1.w);
                afrag[s][ks] = a;
            }
        } else {
            const short* hr = (const short*)hsrc + (size_t)i * 128;
#pragma unroll
            for (int ks = 0; ks < 4; ++ks)
                afrag[s][ks] = *(const bf16x8*)(hr + ks * 32 + gq * 8);
        }
    }

    f32x4 acc[2][NT];
    f32x4 z = {0.f, 0.f, 0.f, 0.f};
    const int NG = NT * 16;

    // ---- phase 1: g = h @ Wl ----
#pragma unroll
    for (int s = 0; s < 2; ++s)
#pragma unroll
        for (int ct = 0; ct < NT; ++ct) acc[s][ct] = z;
#pragma unroll
    for (int ct = 0; ct < NT; ++ct)
#pragma unroll
        for (int ks = 0; ks < 4; ++ks) {
            bf16x8 bfv = *(const bf16x8*)(Wlp + ((size_t)(ct * 4 + ks) * 64 + lane) * 8);
            acc[0][ct] = __builtin_amdgcn_mfma_f32_16x16x32_bf16(afrag[0][ks], bfv, acc[0][ct], 0, 0, 0);
            acc[1][ct] = __builtin_amdgcn_mfma_f32_16x16x32_bf16(afrag[1][ks], bfv, acc[1][ct], 0, 0, 0);
        }
#pragma unroll
    for (int s = 0; s < 2; ++s)
#pragma unroll
        for (int ct = 0; ct < NT; ++ct)
#pragma unroll
            for (int rr = 0; rr < 4; ++rr) {
                int row = rowbase + s * 16 + gq * 4 + rr;
                if (row < n) {
                    float v = acc[s][ct][rr];
                    if (G_FP8) {
                        unsigned pk = __builtin_amdgcn_cvt_pk_fp8_f32(v, v, 0u, false);
                        ((unsigned char*)g)[(size_t)row * NG + ct * 16 + c] = (unsigned char)pk;
                    } else {
                        ((short*)g)[(size_t)row * NG + ct * 16 + c] = f2bf(v);
                    }
                }
            }

    // ---- phase 2: r = h @ Wr + b ----
#pragma unroll
    for (int s = 0; s < 2; ++s)
#pragma unroll
        for (int ct = 0; ct < NT; ++ct) acc[s][ct] = z;
#pragma unroll
    for (int ct = 0; ct < NT; ++ct)
#pragma unroll
        for (int ks = 0; ks < 4; ++ks) {
            bf16x8 bfv = *(const bf16x8*)(Wrp + ((size_t)(ct * 4 + ks) * 64 + lane) * 8);
            acc[0][ct] = __builtin_amdgcn_mfma_f32_16x16x32_bf16(afrag[0][ks], bfv, acc[0][ct], 0, 0, 0);
            acc[1][ct] = __builtin_amdgcn_mfma_f32_16x16x32_bf16(afrag[1][ks], bfv, acc[1][ct], 0, 0, 0);
        }
#pragma unroll
    for (int s = 0; s < 2; ++s)
#pragma unroll
        for (int ct = 0; ct < NT; ++ct)
#pragma unroll
            for (int rr = 0; rr < 4; ++rr) {
                int row = rowbase + s * 16 + gq * 4 + rr;
                if (row < n)
                    r[(size_t)row * 128 + ct * 16 + c] = f2bf(acc[s][ct][rr] + b[ct * 16 + c]);
            }
}

// ---------------- combine (fp8 g): h' = relu(mean_gather(g8) + r) ----------------
__global__ __launch_bounds__(256) void combine_fp8_kernel(
    const unsigned char* __restrict__ g8, const short* rr,
    const int* __restrict__ off, const int* __restrict__ col,
    short* outb, int n) {
    int t = blockIdx.x * 256 + threadIdx.x;
    int node = t >> 4, q = t & 15;
    if (node >= n) return;
    int qo = q * 8;
    int p0 = off[node], p1 = off[node + 1];
    float a[8];
#pragma unroll
    for (int k = 0; k < 8; ++k) a[k] = 0.f;
    int p = p0;
    for (; p + 3 < p1; p += 4) {
        uint2 u0 = *(const uint2*)(g8 + (size_t)col[p] * 128 + qo);
        uint2 u1 = *(const uint2*)(g8 + (size_t)col[p + 1] * 128 + qo);
        uint2 u2 = *(const uint2*)(g8 + (size_t)col[p + 2] * 128 + qo);
        uint2 u3 = *(const uint2*)(g8 + (size_t)col[p + 3] * 128 + qo);
#pragma unroll
        for (int w = 0; w < 4; ++w) {
            uint2 u = (w == 0) ? u0 : (w == 1) ? u1 : (w == 2) ? u2 : u3;
            f32x2 d0 = __builtin_amdgcn_cvt_pk_f32_fp8((int)u.x, false);
            f32x2 d1 = __builtin_amdgcn_cvt_pk_f32_fp8((int)u.x, true);
            f32x2 d2 = __builtin_amdgcn_cvt_pk_f32_fp8((int)u.y, false);
            f32x2 d3 = __builtin_amdgcn_cvt_pk_f32_fp8((int)u.y, true);
            a[0] += d0.x; a[1] += d0.y; a[2] += d1.x; a[3] += d1.y;
            a[4] += d2.x; a[5] += d2.y; a[6] += d3.x; a[7] += d3.y;
        }
    }
    for (; p < p1; ++p) {
        uint2 u = *(const uint2*)(g8 + (size_t)col[p] * 128 + qo);
        f32x2 d0 = __builtin_amdgcn_cvt_pk_f32_fp8((int)u.x, false);
        f32x2 d1 = __builtin_amdgcn_cvt_pk_f32_fp8((int)u.x, true);
        f32x2 d2 = __builtin_amdgcn_cvt_pk_f32_fp8((int)u.y, false);
        f32x2 d3 = __builtin_amdgcn_cvt_pk_f32_fp8((int)u.y, true);
        a[0] += d0.x; a[1] += d0.y; a[2] += d1.x; a[3] += d1.y;
        a[4] += d2.x; a[5] += d2.y; a[6] += d3.x; a[7] += d3.y;
    }
    int deg = p1 - p0;
    float inv = 1.f / (float)(deg > 1 ? deg : 1);
    bf16x8 rv = *(const bf16x8*)(rr + (size_t)node * 128 + qo);
    bf16x8 o;
#pragma unroll
    for (int k = 0; k < 8; ++k) {
        float v = a[k] * inv + bf2f(rv[k]);
        o[k] = f2bf(fmaxf(v, 0.f));
    }
    *(bf16x8*)(outb + (size_t)node * 128 + qo) = o;
}

// ------- combine layer 2 + fused classifier: ne = mean_gather(g) + r ; sc = ne@Wc+bc -
// g rows: 64 bf16 (stride 64). 8 lanes/node. Writes f32 ne + bf16 neb + f32 sc.
__global__ __launch_bounds__(256) void combine_l2_kernel(
    const short* __restrict__ g, const short* rr,
    const int* __restrict__ off, const int* __restrict__ col,
    short* neb, float* nef, const float* __restrict__ Wc,
    const float* __restrict__ bc, float* __restrict__ sc, int n) {
    int t = blockIdx.x * 256 + threadIdx.x;
    int node = t >> 3, q = t & 7;
    if (node >= n) return;
    int qo = q * 8;
    int p0 = off[node], p1 = off[node + 1];
    float a[8];
#pragma unroll
    for (int k = 0; k < 8; ++k) a[k] = 0.f;
    int p = p0;
    for (; p + 3 < p1; p += 4) {
        bf16x8 u0 = *(const bf16x8*)(g + (size_t)col[p] * 64 + qo);
        bf16x8 u1 = *(const bf16x8*)(g + (size_t)col[p + 1] * 64 + qo);
        bf16x8 u2 = *(const bf16x8*)(g + (size_t)col[p + 2] * 64 + qo);
        bf16x8 u3 = *(const bf16x8*)(g + (size_t)col[p + 3] * 64 + qo);
#pragma unroll
        for (int k = 0; k < 8; ++k)
            a[k] += (bf2f(u0[k]) + bf2f(u1[k])) + (bf2f(u2[k]) + bf2f(u3[k]));
    }
    for (; p < p1; ++p) {
        bf16x8 u0 = *(const bf16x8*)(g + (size_t)col[p] * 64 + qo);
#pragma unroll
        for (int k = 0; k < 8; ++k) a[k] += bf2f(u0[k]);
    }
    int deg = p1 - p0;
    float inv = 1.f / (float)(deg > 1 ? deg : 1);
    bf16x8 rv = *(const bf16x8*)(rr + (size_t)node * 128 + qo);
    float val[8];
#pragma unroll
    for (int k = 0; k < 8; ++k) val[k] = a[k] * inv + bf2f(rv[k]);
    float4 f0, f1;
    f0.x = val[0]; f0.y = val[1]; f0.z = val[2]; f0.w = val[3];
    f1.x = val[4]; f1.y = val[5]; f1.z = val[6]; f1.w = val[7];
    *(float4*)(nef + (size_t)node * 64 + qo) = f0;
    *(float4*)(nef + (size_t)node * 64 + qo + 4) = f1;
    bf16x8 o;
#pragma unroll
    for (int k = 0; k < 8; ++k) o[k] = f2bf(val[k]);
    *(bf16x8*)(neb + (size_t)node * 64 + qo) = o;

    // fused classifier: partial dot over this lane's 8 elems, 8-lane shfl reduce
    float part[4];
#pragma unroll
    for (int cidx = 0; cidx < 4; ++cidx) {
        float s0 = 0.f;
#pragma unroll
        for (int k = 0; k < 8; ++k)
            s0 = fmaf(val[k], Wc[(qo + k) * 4 + cidx], s0);
        s0 += __shfl_xor(s0, 1);
        s0 += __shfl_xor(s0, 2);
        s0 += __shfl_xor(s0, 4);
        part[cidx] = s0;
    }
    if (q == 0) {
        float4 o4;
        o4.x = part[0] + bc[0]; o4.y = part[1] + bc[1];
        o4.z = part[2] + bc[2]; o4.w = part[3] + bc[3];
        *(float4*)(sc + (size_t)node * 4) = o4;
    }
}

// ------- edge MLP phase A (dst-grouped CSR order, coalesced position output) -------
__global__ __launch_bounds__(256) void edge_mlp_sorted_kernel(
    const short* __restrict__ neb, const int* __restrict__ col,
    const unsigned short* __restrict__ edst,
    const short* __restrict__ Wp, const float* __restrict__ bf1,
    const float* __restrict__ Wf2, const float* __restrict__ bf2,
    float* __restrict__ cfs, int nE) {
    int wave = (blockIdx.x * 256 + threadIdx.x) >> 6;
    int lane = threadIdx.x & 63;
    int rowbase = wave * 32;
    if (rowbase >= nE) return;
    int g = lane >> 4, c = lane & 15;

    bf16x8 afrag[2][4];
#pragma unroll
    for (int s = 0; s < 2; ++s) {
        int p = rowbase + s * 16 + c;
        const short* rs = neb + (size_t)col[p] * 64;
        const short* rd = neb + (size_t)edst[p] * 64;
        afrag[s][0] = *(const bf16x8*)(rs + g * 8);
        afrag[s][1] = *(const bf16x8*)(rs + 32 + g * 8);
        afrag[s][2] = *(const bf16x8*)(rd + g * 8);
        afrag[s][3] = *(const bf16x8*)(rd + 32 + g * 8);
    }

    f32x4 acc[2][8];
    f32x4 z = {0.f, 0.f, 0.f, 0.f};
#pragma unroll
    for (int s = 0; s < 2; ++s)
#pragma unroll
        for (int ct = 0; ct < 8; ++ct) acc[s][ct] = z;

#pragma unroll
    for (int ct = 0; ct < 8; ++ct)
#pragma unroll
        for (int ks = 0; ks < 4; ++ks) {
            bf16x8 bfv = *(const bf16x8*)(Wp + ((size_t)(ct * 4 + ks) * 64 + lane) * 8);
            acc[0][ct] = __builtin_amdgcn_mfma_f32_16x16x32_bf16(afrag[0][ks], bfv, acc[0][ct], 0, 0, 0);
            acc[1][ct] = __builtin_amdgcn_mfma_f32_16x16x32_bf16(afrag[1][ks], bfv, acc[1][ct], 0, 0, 0);
        }

    float bf1v[8], wf2v[8];
#pragma unroll
    for (int ct = 0; ct < 8; ++ct) {
        bf1v[ct] = bf1[ct * 16 + c];
        wf2v[ct] = Wf2[ct * 16 + c];
    }
    float bias2 = bf2[0];
#pragma unroll
    for (int s = 0; s < 2; ++s)
#pragma unroll
        for (int r = 0; r < 4; ++r) {
            float part = 0.f;
#pragma unroll
            for (int ct = 0; ct < 8; ++ct) {
                float hv = acc[s][ct][r] + bf1v[ct];
                hv = fmaxf(hv, 0.f);
                part = fmaf(hv, wf2v[ct], part);
            }
#pragma unroll
            for (int o = 1; o < 16; o <<= 1)
                part += __shfl_xor(part, o);
            if (c == 0) {
                int row = rowbase + s * 16 + g * 4 + r;
                cfs[row] = part + bias2;
            }
        }
}

// phase B: cf[e] = cfs[pos[e]] (coalesced read/write; random 4B read of L2-resident tbl)
__global__ __launch_bounds__(256) void permute_kernel(const float* __restrict__ cfs,
                                                      const int* __restrict__ pos,
                                                      float* __restrict__ cf, int n) {
    int e = blockIdx.x * 256 + threadIdx.x;
    if (e < n) cf[e] = cfs[pos[e]];
}

// ---------------- edge MLP fallback (original order, direct write) ----------------
__global__ __launch_bounds__(256) void edge_mlp_mfma_kernel(
    const short* __restrict__ neb, const int* __restrict__ src, const int* __restrict__ dst,
    const short* __restrict__ Wp, const float* __restrict__ bf1,
    const float* __restrict__ Wf2, const float* __restrict__ bf2,
    float* __restrict__ out, int nE) {
    int wave = (blockIdx.x * 256 + threadIdx.x) >> 6;
    int lane = threadIdx.x & 63;
    int rowbase = wave * 32;
    if (rowbase >= nE) return;
    int g = lane >> 4, c = lane & 15;

    bf16x8 afrag[2][4];
#pragma unroll
    for (int s = 0; s < 2; ++s) {
        int e = rowbase + s * 16 + c;
        const short* rs = neb + (size_t)src[e] * 64;
        const short* rd = neb + (size_t)dst[e] * 64;
        afrag[s][0] = *(const bf16x8*)(rs + g * 8);
        afrag[s][1] = *(const bf16x8*)(rs + 32 + g * 8);
        afrag[s][2] = *(const bf16x8*)(rd + g * 8);
        afrag[s][3] = *(const bf16x8*)(rd + 32 + g * 8);
    }

    f32x4 acc[2][8];
    f32x4 z = {0.f, 0.f, 0.f, 0.f};
#pragma unroll
    for (int s = 0; s < 2; ++s)
#pragma unroll
        for (int ct = 0; ct < 8; ++ct) acc[s][ct] = z;

#pragma unroll
    for (int ct = 0; ct < 8; ++ct)
#pragma unroll
        for (int ks = 0; ks < 4; ++ks) {
            bf16x8 bfv = *(const bf16x8*)(Wp + ((size_t)(ct * 4 + ks) * 64 + lane) * 8);
            acc[0][ct] = __builtin_amdgcn_mfma_f32_16x16x32_bf16(afrag[0][ks], bfv, acc[0][ct], 0, 0, 0);
            acc[1][ct] = __builtin_amdgcn_mfma_f32_16x16x32_bf16(afrag[1][ks], bfv, acc[1][ct], 0, 0, 0);
        }

    float bf1v[8], wf2v[8];
#pragma unroll
    for (int ct = 0; ct < 8; ++ct) {
        bf1v[ct] = bf1[ct * 16 + c];
        wf2v[ct] = Wf2[ct * 16 + c];
    }
    float bias2 = bf2[0];
#pragma unroll
    for (int s = 0; s < 2; ++s)
#pragma unroll
        for (int r = 0; r < 4; ++r) {
            float part = 0.f;
#pragma unroll
            for (int ct = 0; ct < 8; ++ct) {
                float hv = acc[s][ct][r] + bf1v[ct];
                hv = fmaxf(hv, 0.f);
                part = fmaf(hv, wf2v[ct], part);
            }
#pragma unroll
            for (int o = 1; o < 16; o <<= 1)
                part += __shfl_xor(part, o);
            if (c == 0) {
                int row = rowbase + s * 16 + g * 4 + r;
                out[row] = part + bias2;
            }
        }
}

extern "C" void kernel_launch(void* const* d_in, const int* in_sizes, int n_in,
                              void* d_out, int out_size, void* d_ws, size_t ws_size,
                              hipStream_t stream) {
    const float* x   = (const float*)d_in[0];
    const int*   ei  = (const int*)d_in[1];
    const int*   src = ei;
    const int*   dst = ei + NE;
    const float* Wl0 = (const float*)d_in[2];
    const float* Wr0 = (const float*)d_in[3];
    const float* b0  = (const float*)d_in[4];
    const float* Wl1 = (const float*)d_in[5];
    const float* Wr1 = (const float*)d_in[6];
    const float* b1  = (const float*)d_in[7];
    const float* Wl2 = (const float*)d_in[8];
    const float* Wr2 = (const float*)d_in[9];
    const float* b2  = (const float*)d_in[10];
    const float* Wf1 = (const float*)d_in[11];
    const float* bf1 = (const float*)d_in[12];
    const float* Wf2 = (const float*)d_in[13];
    const float* bf2 = (const float*)d_in[14];
    const float* Wc  = (const float*)d_in[15];
    const float* bc  = (const float*)d_in[16];

    // ---- workspace carve-up (base ~29.4 MB; +4.8 MB sorted-edge path = 34.2 MB) ----
    short* sp = (short*)d_ws;
    short* W0lp = sp; sp += 128 * 128;
    short* W0rp = sp; sp += 128 * 128;
    short* W1lp = sp; sp += 128 * 128;
    short* W1rp = sp; sp += 128 * 128;
    short* W2lp = sp; sp += 128 * 64;
    short* W2rp = sp; sp += 128 * 64;
    short* Wfp  = sp; sp += 128 * 128;
    short* gb   = sp; sp += (size_t)NN * 64;    // 6.4 MB: fp8 g[NN,128]B | bf16 g2[NN,64] | cfs
    short* hb   = sp; sp += (size_t)NN * 128;   // 12.8 MB: r/h rows (in place)
    short* neb  = sp; sp += (size_t)NN * 64;    // 6.4 MB: compact bf16 node embeddings
    int* ip = (int*)sp;
    int* off    = ip; ip += 50008;
    int* cursor = ip; ip += 50000;               // also deg
    int* col    = ip; ip += 800000;
    int* bsum   = ip; ip += 256;

    const bool sorted = ws_size >= (size_t)34300000;
    int* pos = nullptr;
    unsigned short* edst = nullptr;
    if (sorted) {
        pos  = ip; ip += NE;                      // 3.2 MB
        edst = (unsigned short*)ip;               // 1.6 MB
    }
    float* cfs = (float*)gb;                      // aliases gb (free after combine_l2)

    float* ne = (float*)d_out;               // [NN,64]
    float* cf = ne + (size_t)NN * 64;        // [NE]
    float* sc = cf + NE;                     // [NN,4]

    int* deg = cursor;
    const int NB = (NN + 255) / 256;

    // --- CSR build ---
    hipMemsetAsync(deg, 0, NN * sizeof(int), stream);
    count_deg_kernel<<<(NE + 255) / 256, 256, 0, stream>>>(dst, deg, NE);
    scan1_kernel<<<NB, 256, 0, stream>>>(deg, off, bsum, NN);
    scan2_kernel<<<1, 256, 0, stream>>>(bsum, NB);
    scan3_kernel<<<NB, 256, 0, stream>>>(off, bsum, cursor, NN, NE);
    fill_kernel<<<(NE + 255) / 256, 256, 0, stream>>>(src, dst, cursor, col, pos, NE);
    if (sorted)
        edst_fill_kernel<<<NB, 256, 0, stream>>>(off, edst, NN);

    // --- weight packs ---
    pack_all_kernel<<<48, 256, 0, stream>>>(Wl0, Wr0, Wl1, Wr1, Wl2, Wr2, Wf1,
                                            W0lp, W0rp, W1lp, W1rp, W2lp, W2rp, Wfp);

    int sgrid  = ((NN + 31) / 32 + 3) / 4;       // 391
    int cgrid1 = (NN * 16 + 255) / 256;          // 3125
    int cgrid2 = (NN * 8 + 255) / 256;           // 1563
    int egrid  = (NE / 32) / 4;                  // 6250

    // --- layer 0: A from f32 x; g0 fp8 -> gb; r0 -> hb; combine -> hb ---
    gemm_tf_kernel<8, true, true><<<sgrid, 256, 0, stream>>>(x, W0lp, W0rp, b0, gb, hb, NN);
    combine_fp8_kernel<<<cgrid1, 256, 0, stream>>>((const unsigned char*)gb, hb, off, col, hb, NN);
    // --- layer 1 ---
    gemm_tf_kernel<8, false, true><<<sgrid, 256, 0, stream>>>(hb, W1lp, W1rp, b1, gb, hb, NN);
    combine_fp8_kernel<<<cgrid1, 256, 0, stream>>>((const unsigned char*)gb, hb, off, col, hb, NN);
    // --- layer 2: g2 bf16 64-wide -> gb; r2 -> hb; combine -> ne + neb + sc (fused) ---
    gemm_tf_kernel<4, false, false><<<sgrid, 256, 0, stream>>>(hb, W2lp, W2rp, b2, gb, hb, NN);
    combine_l2_kernel<<<cgrid2, 256, 0, stream>>>(gb, hb, off, col, neb, ne, Wc, bc, sc, NN);

    // --- edge head ---
    if (sorted) {
        edge_mlp_sorted_kernel<<<egrid, 256, 0, stream>>>(neb, col, edst, Wfp, bf1, Wf2, bf2, cfs, NE);
        permute_kernel<<<(NE + 255) / 256, 256, 0, stream>>>(cfs, pos, cf, NE);
    } else {
        edge_mlp_mfma_kernel<<<egrid, 256, 0, stream>>>(neb, src, dst, Wfp, bf1, Wf2, bf2, cf, NE);
    }
}

// Round 10
// 301.411 us; speedup vs baseline: 1.1917x; 1.0066x over previous
//
#include <hip/hip_runtime.h>

#define NN 50000
#define NE 800000

typedef __attribute__((ext_vector_type(8))) short bf16x8;
typedef __attribute__((ext_vector_type(4))) float f32x4;
typedef __attribute__((ext_vector_type(2))) float f32x2;

__device__ inline short f2bf(float f) {
    union { float f; unsigned u; } v; v.f = f;
    unsigned r = v.u + 0x7fffu + ((v.u >> 16) & 1u);
    return (short)(r >> 16);
}
__device__ inline float bf2f(short s) {
    union { unsigned u; float f; } v;
    v.u = ((unsigned)(unsigned short)s) << 16;
    return v.f;
}

// ---------------- CSR build ----------------
__global__ __launch_bounds__(256) void count_deg_kernel(const int* __restrict__ dst,
                                                        int* __restrict__ deg, int n) {
    int e = blockIdx.x * 256 + threadIdx.x;
    if (e < n) atomicAdd(&deg[dst[e]], 1);
}

__global__ __launch_bounds__(256) void scan1_kernel(const int* __restrict__ deg,
                                                    int* __restrict__ off,
                                                    int* __restrict__ bsum, int n) {
    __shared__ int s[256];
    int t = threadIdx.x;
    int i = blockIdx.x * 256 + t;
    int v = (i < n) ? deg[i] : 0;
    s[t] = v;
    __syncthreads();
    for (int d = 1; d < 256; d <<= 1) {
        int u = (t >= d) ? s[t - d] : 0;
        __syncthreads();
        s[t] += u;
        __syncthreads();
    }
    if (i < n) off[i] = s[t] - v;
    if (t == 255) bsum[blockIdx.x] = s[255];
}

// merged: block-prefix of bsum + global off/cursor + edst fill
// cursor aliases deg (deg read before overwrite, same thread)
__global__ __launch_bounds__(256) void scan3x_kernel(
    int* __restrict__ off, const int* __restrict__ bsum,
    int* __restrict__ cursor, unsigned short* __restrict__ edst,
    int n, int total, int nb) {
    __shared__ int s[256];
    int t = threadIdx.x;
    int v = (t < nb) ? bsum[t] : 0;
    s[t] = v;
    __syncthreads();
    for (int d = 1; d < 256; d <<= 1) {
        int u = (t >= d) ? s[t - d] : 0;
        __syncthreads();
        s[t] += u;
        __syncthreads();
    }
    int base = (blockIdx.x == 0) ? 0 : s[blockIdx.x - 1];
    int i = blockIdx.x * 256 + t;
    if (i < n) {
        int d = cursor[i];            // deg
        int v2 = off[i] + base;
        off[i] = v2;
        cursor[i] = v2;
        if (edst)
            for (int p = v2; p < v2 + d; ++p) edst[p] = (unsigned short)i;
    }
    if (i == 0) off[n] = total;
}

// fill CSR; record pos[e] = CSR position of edge e (coalesced by e)
__global__ __launch_bounds__(256) void fill_kernel(const int* __restrict__ src,
                                                   const int* __restrict__ dst,
                                                   int* __restrict__ cursor,
                                                   int* __restrict__ col,
                                                   int* __restrict__ pos, int n) {
    int e = blockIdx.x * 256 + threadIdx.x;
    if (e < n) {
        int p = atomicAdd(&cursor[dst[e]], 1);
        col[p] = src[e];
        if (pos) pos[e] = p;
    }
}

// ---------------- pack one f32 KxN matrix into bf16 MFMA B-fragments --------------
__device__ inline void pack_one(const float* B, int K, int N, short* out, int t) {
    int l = t & 63;
    int fs = t >> 6;
    int KS = K >> 5;
    int ct = fs / KS, ks = fs - ct * KS;
    int coln = ct * 16 + (l & 15);
    int k0 = ks * 32 + (l >> 4) * 8;
    bf16x8 v;
#pragma unroll
    for (int j = 0; j < 8; ++j)
        v[j] = f2bf(B[(size_t)(k0 + j) * N + coln]);
    *(bf16x8*)(out + (size_t)t * 8) = v;
}

__global__ __launch_bounds__(256) void pack_all_kernel(
    const float* __restrict__ Wl0, const float* __restrict__ Wr0,
    const float* __restrict__ Wl1, const float* __restrict__ Wr1,
    const float* __restrict__ Wl2, const float* __restrict__ Wr2,
    const float* __restrict__ Wf1,
    short* W0lp, short* W0rp, short* W1lp, short* W1rp,
    short* W2lp, short* W2rp, short* Wfp) {
    int t = blockIdx.x * 256 + threadIdx.x;
    if (t < 2048)              pack_one(Wl0, 128, 128, W0lp, t);
    else if (t < 4096)         pack_one(Wr0, 128, 128, W0rp, t - 2048);
    else if (t < 6144)         pack_one(Wl1, 128, 128, W1lp, t - 4096);
    else if (t < 8192)         pack_one(Wr1, 128, 128, W1rp, t - 6144);
    else if (t < 9216)         pack_one(Wl2, 128, 64,  W2lp, t - 8192);
    else if (t < 10240)        pack_one(Wr2, 128, 64,  W2rp, t - 9216);
    else if (t < 12288)        pack_one(Wf1, 128, 128, Wfp,  t - 10240);
}

// ---------------- transform GEMM: g = h@Wl ; r = h@Wr + b  (K=128) ----------------
template <int NT, bool SRC_F32, bool G_FP8>
__global__ __launch_bounds__(256) void gemm_tf_kernel(
    const void* hsrc, const short* __restrict__ Wlp, const short* __restrict__ Wrp,
    const float* __restrict__ b, void* g, short* r, int n) {
    int wave = (blockIdx.x * 256 + threadIdx.x) >> 6;
    int lane = threadIdx.x & 63;
    int rowbase = wave * 32;
    if (rowbase >= n) return;
    int gq = lane >> 4, c = lane & 15;

    bf16x8 afrag[2][4];
#pragma unroll
    for (int s = 0; s < 2; ++s) {
        int i = rowbase + s * 16 + c;
        if (i >= n) i = n - 1;
        if (SRC_F32) {
            const float* xr = (const float*)hsrc + (size_t)i * 128;
#pragma unroll
            for (int ks = 0; ks < 4; ++ks) {
                const float* p = xr + ks * 32 + gq * 8;
                float4 v0 = *(const float4*)p;
                float4 v1 = *(const float4*)(p + 4);
                bf16x8 a;
                a[0] = f2bf(v0.x); a[1] = f2bf(v0.y); a[2] = f2bf(v0.z); a[3] = f2bf(v0.w);
                a[4] = f2bf(v1.x); a[5] = f2bf(v1.y); a[6] = f2bf(v1.z); a[7] = f2bf(v1.w);
                afrag[s][ks] = a;
            }
        } else {
            const short* hr = (const short*)hsrc + (size_t)i * 128;
#pragma unroll
            for (int ks = 0; ks < 4; ++ks)
                afrag[s][ks] = *(const bf16x8*)(hr + ks * 32 + gq * 8);
        }
    }

    f32x4 acc[2][NT];
    f32x4 z = {0.f, 0.f, 0.f, 0.f};
    const int NG = NT * 16;

    // ---- phase 1: g = h @ Wl ----
#pragma unroll
    for (int s = 0; s < 2; ++s)
#pragma unroll
        for (int ct = 0; ct < NT; ++ct) acc[s][ct] = z;
#pragma unroll
    for (int ct = 0; ct < NT; ++ct)
#pragma unroll
        for (int ks = 0; ks < 4; ++ks) {
            bf16x8 bfv = *(const bf16x8*)(Wlp + ((size_t)(ct * 4 + ks) * 64 + lane) * 8);
            acc[0][ct] = __builtin_amdgcn_mfma_f32_16x16x32_bf16(afrag[0][ks], bfv, acc[0][ct], 0, 0, 0);
            acc[1][ct] = __builtin_amdgcn_mfma_f32_16x16x32_bf16(afrag[1][ks], bfv, acc[1][ct], 0, 0, 0);
        }
#pragma unroll
    for (int s = 0; s < 2; ++s)
#pragma unroll
        for (int ct = 0; ct < NT; ++ct)
#pragma unroll
            for (int rr = 0; rr < 4; ++rr) {
                int row = rowbase + s * 16 + gq * 4 + rr;
                if (row < n) {
                    float v = acc[s][ct][rr];
                    if (G_FP8) {
                        unsigned pk = __builtin_amdgcn_cvt_pk_fp8_f32(v, v, 0u, false);
                        ((unsigned char*)g)[(size_t)row * NG + ct * 16 + c] = (unsigned char)pk;
                    } else {
                        ((short*)g)[(size_t)row * NG + ct * 16 + c] = f2bf(v);
                    }
                }
            }

    // ---- phase 2: r = h @ Wr + b ----
#pragma unroll
    for (int s = 0; s < 2; ++s)
#pragma unroll
        for (int ct = 0; ct < NT; ++ct) acc[s][ct] = z;
#pragma unroll
    for (int ct = 0; ct < NT; ++ct)
#pragma unroll
        for (int ks = 0; ks < 4; ++ks) {
            bf16x8 bfv = *(const bf16x8*)(Wrp + ((size_t)(ct * 4 + ks) * 64 + lane) * 8);
            acc[0][ct] = __builtin_amdgcn_mfma_f32_16x16x32_bf16(afrag[0][ks], bfv, acc[0][ct], 0, 0, 0);
            acc[1][ct] = __builtin_amdgcn_mfma_f32_16x16x32_bf16(afrag[1][ks], bfv, acc[1][ct], 0, 0, 0);
        }
#pragma unroll
    for (int s = 0; s < 2; ++s)
#pragma unroll
        for (int ct = 0; ct < NT; ++ct)
#pragma unroll
            for (int rr = 0; rr < 4; ++rr) {
                int row = rowbase + s * 16 + gq * 4 + rr;
                if (row < n)
                    r[(size_t)row * 128 + ct * 16 + c] = f2bf(acc[s][ct][rr] + b[ct * 16 + c]);
            }
}

// ---------------- combine (fp8 g): h' = relu(mean_gather(g8) + r) ----------------
// 8 lanes/node, uint4 (16B) per lane: one instruction = full 128-B row x 8 nodes.
__device__ inline void acc_fp8x16(unsigned x, unsigned y, unsigned z, unsigned w, float* a) {
    f32x2 d;
    d = __builtin_amdgcn_cvt_pk_f32_fp8((int)x, false); a[0] += d.x;  a[1] += d.y;
    d = __builtin_amdgcn_cvt_pk_f32_fp8((int)x, true);  a[2] += d.x;  a[3] += d.y;
    d = __builtin_amdgcn_cvt_pk_f32_fp8((int)y, false); a[4] += d.x;  a[5] += d.y;
    d = __builtin_amdgcn_cvt_pk_f32_fp8((int)y, true);  a[6] += d.x;  a[7] += d.y;
    d = __builtin_amdgcn_cvt_pk_f32_fp8((int)z, false); a[8] += d.x;  a[9] += d.y;
    d = __builtin_amdgcn_cvt_pk_f32_fp8((int)z, true);  a[10] += d.x; a[11] += d.y;
    d = __builtin_amdgcn_cvt_pk_f32_fp8((int)w, false); a[12] += d.x; a[13] += d.y;
    d = __builtin_amdgcn_cvt_pk_f32_fp8((int)w, true);  a[14] += d.x; a[15] += d.y;
}

__global__ __launch_bounds__(256) void combine_fp8_kernel(
    const unsigned char* __restrict__ g8, const short* rr,
    const int* __restrict__ off, const int* __restrict__ col,
    short* outb, int n) {
    int t = blockIdx.x * 256 + threadIdx.x;
    int node = t >> 3, q = t & 7;
    if (node >= n) return;
    int qo = q * 16;                 // byte offset within 128-B row
    int p0 = off[node], p1 = off[node + 1];
    float a[16];
#pragma unroll
    for (int k = 0; k < 16; ++k) a[k] = 0.f;
    int p = p0;
    for (; p + 3 < p1; p += 4) {
        uint4 u0 = *(const uint4*)(g8 + (size_t)col[p] * 128 + qo);
        uint4 u1 = *(const uint4*)(g8 + (size_t)col[p + 1] * 128 + qo);
        uint4 u2 = *(const uint4*)(g8 + (size_t)col[p + 2] * 128 + qo);
        uint4 u3 = *(const uint4*)(g8 + (size_t)col[p + 3] * 128 + qo);
        acc_fp8x16(u0.x, u0.y, u0.z, u0.w, a);
        acc_fp8x16(u1.x, u1.y, u1.z, u1.w, a);
        acc_fp8x16(u2.x, u2.y, u2.z, u2.w, a);
        acc_fp8x16(u3.x, u3.y, u3.z, u3.w, a);
    }
    for (; p < p1; ++p) {
        uint4 u = *(const uint4*)(g8 + (size_t)col[p] * 128 + qo);
        acc_fp8x16(u.x, u.y, u.z, u.w, a);
    }
    int deg = p1 - p0;
    float inv = 1.f / (float)(deg > 1 ? deg : 1);
    const short* rrow = rr + (size_t)node * 128 + q * 16;
    bf16x8 rv0 = *(const bf16x8*)rrow;
    bf16x8 rv1 = *(const bf16x8*)(rrow + 8);
    bf16x8 o0, o1;
#pragma unroll
    for (int k = 0; k < 8; ++k) {
        o0[k] = f2bf(fmaxf(a[k] * inv + bf2f(rv0[k]), 0.f));
        o1[k] = f2bf(fmaxf(a[k + 8] * inv + bf2f(rv1[k]), 0.f));
    }
    short* orow = outb + (size_t)node * 128 + q * 16;
    *(bf16x8*)orow = o0;
    *(bf16x8*)(orow + 8) = o1;
}

// ------- combine layer 2 + fused classifier: ne = mean_gather(g) + r ; sc = ne@Wc+bc -
__global__ __launch_bounds__(256) void combine_l2_kernel(
    const short* __restrict__ g, const short* rr,
    const int* __restrict__ off, const int* __restrict__ col,
    short* neb, float* nef, const float* __restrict__ Wc,
    const float* __restrict__ bc, float* __restrict__ sc, int n) {
    int t = blockIdx.x * 256 + threadIdx.x;
    int node = t >> 3, q = t & 7;
    if (node >= n) return;
    int qo = q * 8;
    int p0 = off[node], p1 = off[node + 1];
    float a[8];
#pragma unroll
    for (int k = 0; k < 8; ++k) a[k] = 0.f;
    int p = p0;
    for (; p + 3 < p1; p += 4) {
        bf16x8 u0 = *(const bf16x8*)(g + (size_t)col[p] * 64 + qo);
        bf16x8 u1 = *(const bf16x8*)(g + (size_t)col[p + 1] * 64 + qo);
        bf16x8 u2 = *(const bf16x8*)(g + (size_t)col[p + 2] * 64 + qo);
        bf16x8 u3 = *(const bf16x8*)(g + (size_t)col[p + 3] * 64 + qo);
#pragma unroll
        for (int k = 0; k < 8; ++k)
            a[k] += (bf2f(u0[k]) + bf2f(u1[k])) + (bf2f(u2[k]) + bf2f(u3[k]));
    }
    for (; p < p1; ++p) {
        bf16x8 u0 = *(const bf16x8*)(g + (size_t)col[p] * 64 + qo);
#pragma unroll
        for (int k = 0; k < 8; ++k) a[k] += bf2f(u0[k]);
    }
    int deg = p1 - p0;
    float inv = 1.f / (float)(deg > 1 ? deg : 1);
    bf16x8 rv = *(const bf16x8*)(rr + (size_t)node * 128 + qo);
    float val[8];
#pragma unroll
    for (int k = 0; k < 8; ++k) val[k] = a[k] * inv + bf2f(rv[k]);
    float4 f0, f1;
    f0.x = val[0]; f0.y = val[1]; f0.z = val[2]; f0.w = val[3];
    f1.x = val[4]; f1.y = val[5]; f1.z = val[6]; f1.w = val[7];
    *(float4*)(nef + (size_t)node * 64 + qo) = f0;
    *(float4*)(nef + (size_t)node * 64 + qo + 4) = f1;
    bf16x8 o;
#pragma unroll
    for (int k = 0; k < 8; ++k) o[k] = f2bf(val[k]);
    *(bf16x8*)(neb + (size_t)node * 64 + qo) = o;

    float part[4];
#pragma unroll
    for (int cidx = 0; cidx < 4; ++cidx) {
        float s0 = 0.f;
#pragma unroll
        for (int k = 0; k < 8; ++k)
            s0 = fmaf(val[k], Wc[(qo + k) * 4 + cidx], s0);
        s0 += __shfl_xor(s0, 1);
        s0 += __shfl_xor(s0, 2);
        s0 += __shfl_xor(s0, 4);
        part[cidx] = s0;
    }
    if (q == 0) {
        float4 o4;
        o4.x = part[0] + bc[0]; o4.y = part[1] + bc[1];
        o4.z = part[2] + bc[2]; o4.w = part[3] + bc[3];
        *(float4*)(sc + (size_t)node * 4) = o4;
    }
}

// ------- edge MLP phase A (dst-grouped CSR order, coalesced position output) -------
__global__ __launch_bounds__(256) void edge_mlp_sorted_kernel(
    const short* __restrict__ neb, const int* __restrict__ col,
    const unsigned short* __restrict__ edst,
    const short* __restrict__ Wp, const float* __restrict__ bf1,
    const float* __restrict__ Wf2, const float* __restrict__ bf2,
    float* __restrict__ cfs, int nE) {
    int wave = (blockIdx.x * 256 + threadIdx.x) >> 6;
    int lane = threadIdx.x & 63;
    int rowbase = wave * 32;
    if (rowbase >= nE) return;
    int g = lane >> 4, c = lane & 15;

    bf16x8 afrag[2][4];
#pragma unroll
    for (int s = 0; s < 2; ++s) {
        int p = rowbase + s * 16 + c;
        const short* rs = neb + (size_t)col[p] * 64;
        const short* rd = neb + (size_t)edst[p] * 64;
        afrag[s][0] = *(const bf16x8*)(rs + g * 8);
        afrag[s][1] = *(const bf16x8*)(rs + 32 + g * 8);
        afrag[s][2] = *(const bf16x8*)(rd + g * 8);
        afrag[s][3] = *(const bf16x8*)(rd + 32 + g * 8);
    }

    f32x4 acc[2][8];
    f32x4 z = {0.f, 0.f, 0.f, 0.f};
#pragma unroll
    for (int s = 0; s < 2; ++s)
#pragma unroll
        for (int ct = 0; ct < 8; ++ct) acc[s][ct] = z;

#pragma unroll
    for (int ct = 0; ct < 8; ++ct)
#pragma unroll
        for (int ks = 0; ks < 4; ++ks) {
            bf16x8 bfv = *(const bf16x8*)(Wp + ((size_t)(ct * 4 + ks) * 64 + lane) * 8);
            acc[0][ct] = __builtin_amdgcn_mfma_f32_16x16x32_bf16(afrag[0][ks], bfv, acc[0][ct], 0, 0, 0);
            acc[1][ct] = __builtin_amdgcn_mfma_f32_16x16x32_bf16(afrag[1][ks], bfv, acc[1][ct], 0, 0, 0);
        }

    float bf1v[8], wf2v[8];
#pragma unroll
    for (int ct = 0; ct < 8; ++ct) {
        bf1v[ct] = bf1[ct * 16 + c];
        wf2v[ct] = Wf2[ct * 16 + c];
    }
    float bias2 = bf2[0];
#pragma unroll
    for (int s = 0; s < 2; ++s)
#pragma unroll
        for (int r = 0; r < 4; ++r) {
            float part = 0.f;
#pragma unroll
            for (int ct = 0; ct < 8; ++ct) {
                float hv = acc[s][ct][r] + bf1v[ct];
                hv = fmaxf(hv, 0.f);
                part = fmaf(hv, wf2v[ct], part);
            }
#pragma unroll
            for (int o = 1; o < 16; o <<= 1)
                part += __shfl_xor(part, o);
            if (c == 0) {
                int row = rowbase + s * 16 + g * 4 + r;
                cfs[row] = part + bias2;
            }
        }
}

// phase B: cf[e] = cfs[pos[e]]
__global__ __launch_bounds__(256) void permute_kernel(const float* __restrict__ cfs,
                                                      const int* __restrict__ pos,
                                                      float* __restrict__ cf, int n) {
    int e = blockIdx.x * 256 + threadIdx.x;
    if (e < n) cf[e] = cfs[pos[e]];
}

// ---------------- edge MLP fallback (original order, direct write) ----------------
__global__ __launch_bounds__(256) void edge_mlp_mfma_kernel(
    const short* __restrict__ neb, const int* __restrict__ src, const int* __restrict__ dst,
    const short* __restrict__ Wp, const float* __restrict__ bf1,
    const float* __restrict__ Wf2, const float* __restrict__ bf2,
    float* __restrict__ out, int nE) {
    int wave = (blockIdx.x * 256 + threadIdx.x) >> 6;
    int lane = threadIdx.x & 63;
    int rowbase = wave * 32;
    if (rowbase >= nE) return;
    int g = lane >> 4, c = lane & 15;

    bf16x8 afrag[2][4];
#pragma unroll
    for (int s = 0; s < 2; ++s) {
        int e = rowbase + s * 16 + c;
        const short* rs = neb + (size_t)src[e] * 64;
        const short* rd = neb + (size_t)dst[e] * 64;
        afrag[s][0] = *(const bf16x8*)(rs + g * 8);
        afrag[s][1] = *(const bf16x8*)(rs + 32 + g * 8);
        afrag[s][2] = *(const bf16x8*)(rd + g * 8);
        afrag[s][3] = *(const bf16x8*)(rd + 32 + g * 8);
    }

    f32x4 acc[2][8];
    f32x4 z = {0.f, 0.f, 0.f, 0.f};
#pragma unroll
    for (int s = 0; s < 2; ++s)
#pragma unroll
        for (int ct = 0; ct < 8; ++ct) acc[s][ct] = z;

#pragma unroll
    for (int ct = 0; ct < 8; ++ct)
#pragma unroll
        for (int ks = 0; ks < 4; ++ks) {
            bf16x8 bfv = *(const bf16x8*)(Wp + ((size_t)(ct * 4 + ks) * 64 + lane) * 8);
            acc[0][ct] = __builtin_amdgcn_mfma_f32_16x16x32_bf16(afrag[0][ks], bfv, acc[0][ct], 0, 0, 0);
            acc[1][ct] = __builtin_amdgcn_mfma_f32_16x16x32_bf16(afrag[1][ks], bfv, acc[1][ct], 0, 0, 0);
        }

    float bf1v[8], wf2v[8];
#pragma unroll
    for (int ct = 0; ct < 8; ++ct) {
        bf1v[ct] = bf1[ct * 16 + c];
        wf2v[ct] = Wf2[ct * 16 + c];
    }
    float bias2 = bf2[0];
#pragma unroll
    for (int s = 0; s < 2; ++s)
#pragma unroll
        for (int r = 0; r < 4; ++r) {
            float part = 0.f;
#pragma unroll
            for (int ct = 0; ct < 8; ++ct) {
                float hv = acc[s][ct][r] + bf1v[ct];
                hv = fmaxf(hv, 0.f);
                part = fmaf(hv, wf2v[ct], part);
            }
#pragma unroll
            for (int o = 1; o < 16; o <<= 1)
                part += __shfl_xor(part, o);
            if (c == 0) {
                int row = rowbase + s * 16 + g * 4 + r;
                out[row] = part + bias2;
            }
        }
}

extern "C" void kernel_launch(void* const* d_in, const int* in_sizes, int n_in,
                              void* d_out, int out_size, void* d_ws, size_t ws_size,
                              hipStream_t stream) {
    const float* x   = (const float*)d_in[0];
    const int*   ei  = (const int*)d_in[1];
    const int*   src = ei;
    const int*   dst = ei + NE;
    const float* Wl0 = (const float*)d_in[2];
    const float* Wr0 = (const float*)d_in[3];
    const float* b0  = (const float*)d_in[4];
    const float* Wl1 = (const float*)d_in[5];
    const float* Wr1 = (const float*)d_in[6];
    const float* b1  = (const float*)d_in[7];
    const float* Wl2 = (const float*)d_in[8];
    const float* Wr2 = (const float*)d_in[9];
    const float* b2  = (const float*)d_in[10];
    const float* Wf1 = (const float*)d_in[11];
    const float* bf1 = (const float*)d_in[12];
    const float* Wf2 = (const float*)d_in[13];
    const float* bf2 = (const float*)d_in[14];
    const float* Wc  = (const float*)d_in[15];
    const float* bc  = (const float*)d_in[16];

    // ---- workspace carve-up (base ~29.4 MB; +4.8 MB sorted-edge path = 34.2 MB) ----
    short* sp = (short*)d_ws;
    short* W0lp = sp; sp += 128 * 128;
    short* W0rp = sp; sp += 128 * 128;
    short* W1lp = sp; sp += 128 * 128;
    short* W1rp = sp; sp += 128 * 128;
    short* W2lp = sp; sp += 128 * 64;
    short* W2rp = sp; sp += 128 * 64;
    short* Wfp  = sp; sp += 128 * 128;
    short* gb   = sp; sp += (size_t)NN * 64;    // 6.4 MB: fp8 g[NN,128]B | bf16 g2[NN,64] | cfs
    short* hb   = sp; sp += (size_t)NN * 128;   // 12.8 MB: r/h rows (in place)
    short* neb  = sp; sp += (size_t)NN * 64;    // 6.4 MB: compact bf16 node embeddings
    int* ip = (int*)sp;
    int* off    = ip; ip += 50008;
    int* cursor = ip; ip += 50000;               // also deg
    int* col    = ip; ip += 800000;
    int* bsum   = ip; ip += 256;

    const bool sorted = ws_size >= (size_t)34300000;
    int* pos = nullptr;
    unsigned short* edst = nullptr;
    if (sorted) {
        pos  = ip; ip += NE;                      // 3.2 MB
        edst = (unsigned short*)ip;               // 1.6 MB
    }
    float* cfs = (float*)gb;                      // aliases gb (free after combine_l2)

    float* ne = (float*)d_out;               // [NN,64]
    float* cf = ne + (size_t)NN * 64;        // [NE]
    float* sc = cf + NE;                     // [NN,4]

    int* deg = cursor;
    const int NB = (NN + 255) / 256;

    // --- CSR build (5 dispatches) ---
    hipMemsetAsync(deg, 0, NN * sizeof(int), stream);
    count_deg_kernel<<<(NE + 255) / 256, 256, 0, stream>>>(dst, deg, NE);
    scan1_kernel<<<NB, 256, 0, stream>>>(deg, off, bsum, NN);
    scan3x_kernel<<<NB, 256, 0, stream>>>(off, bsum, cursor, edst, NN, NE, NB);
    fill_kernel<<<(NE + 255) / 256, 256, 0, stream>>>(src, dst, cursor, col, pos, NE);

    // --- weight packs ---
    pack_all_kernel<<<48, 256, 0, stream>>>(Wl0, Wr0, Wl1, Wr1, Wl2, Wr2, Wf1,
                                            W0lp, W0rp, W1lp, W1rp, W2lp, W2rp, Wfp);

    int sgrid  = ((NN + 31) / 32 + 3) / 4;       // 391
    int cgridf = (NN * 8 + 255) / 256;           // 1563 (8 lanes/node)
    int cgrid2 = (NN * 8 + 255) / 256;           // 1563
    int egrid  = (NE / 32) / 4;                  // 6250

    // --- layer 0: A from f32 x; g0 fp8 -> gb; r0 -> hb; combine -> hb ---
    gemm_tf_kernel<8, true, true><<<sgrid, 256, 0, stream>>>(x, W0lp, W0rp, b0, gb, hb, NN);
    combine_fp8_kernel<<<cgridf, 256, 0, stream>>>((const unsigned char*)gb, hb, off, col, hb, NN);
    // --- layer 1 ---
    gemm_tf_kernel<8, false, true><<<sgrid, 256, 0, stream>>>(hb, W1lp, W1rp, b1, gb, hb, NN);
    combine_fp8_kernel<<<cgridf, 256, 0, stream>>>((const unsigned char*)gb, hb, off, col, hb, NN);
    // --- layer 2: g2 bf16 64-wide -> gb; r2 -> hb; combine -> ne + neb + sc (fused) ---
    gemm_tf_kernel<4, false, false><<<sgrid, 256, 0, stream>>>(hb, W2lp, W2rp, b2, gb, hb, NN);
    combine_l2_kernel<<<cgrid2, 256, 0, stream>>>(gb, hb, off, col, neb, ne, Wc, bc, sc, NN);

    // --- edge head ---
    if (sorted) {
        edge_mlp_sorted_kernel<<<egrid, 256, 0, stream>>>(neb, col, edst, Wfp, bf1, Wf2, bf2, cfs, NE);
        permute_kernel<<<(NE + 255) / 256, 256, 0, stream>>>(cfs, pos, cf, NE);
    } else {
        edge_mlp_mfma_kernel<<<egrid, 256, 0, stream>>>(neb, src, dst, Wfp, bf1, Wf2, bf2, cf, NE);
    }
}